// Round 3
// 3089.093 us; speedup vs baseline: 2.0128x; 2.0128x over previous
//
#include <hip/hip_runtime.h>

typedef unsigned short u16;
typedef __bf16 bf16x8 __attribute__((ext_vector_type(8)));
typedef float f32x4 __attribute__((ext_vector_type(4)));

static __device__ __forceinline__ float bf2f(u16 v){ unsigned u=((unsigned)v)<<16; float f; __builtin_memcpy(&f,&u,4); return f; }
static __device__ __forceinline__ u16 f2bf(float f){ unsigned u; __builtin_memcpy(&u,&f,4); u += 0x7fffu + ((u>>16)&1u); return (u16)(u>>16); }

static __device__ __forceinline__ float wave_max(float v){
#pragma unroll
  for(int o=32;o;o>>=1) v=fmaxf(v,__shfl_xor(v,o,64));
  return v;
}
static __device__ __forceinline__ float wave_sum(float v){
#pragma unroll
  for(int o=32;o;o>>=1) v+=__shfl_xor(v,o,64);
  return v;
}

__global__ void k_sentinel(u16* __restrict__ o, float v){ o[0] = f2bf(v); }

// dtype probe: if any u16 half of x's first 32768 words has exponent field 0xFF,
// the data cannot be finite bf16 -> it is f32 mantissa bits. flag=1 => f32 inputs.
__global__ void k_probe(const unsigned* __restrict__ w, int* __restrict__ flag){
  __shared__ int found;
  if (threadIdx.x==0) found = 0;
  __syncthreads();
  int loc = 0;
  for (int i = threadIdx.x; i < 32768; i += 256){
    unsigned v = w[i];
    if ((((v >> 7) & 0xFFu) == 0xFFu) || (((v >> 23) & 0xFFu) == 0xFFu)) loc = 1;
  }
  if (loc) atomicOr(&found, 1);
  __syncthreads();
  if (threadIdx.x==0) *flag = found;
}

// normalize a tensor to bf16 (identity copy if already bf16)
__global__ void k_cvt(const void* __restrict__ src, u16* __restrict__ dst, int n, const int* __restrict__ flag){
  int i = blockIdx.x*256 + threadIdx.x;
  if (i >= n) return;
  if (*flag) dst[i] = f2bf(((const float*)src)[i]);
  else       dst[i] = ((const u16*)src)[i];
}

__global__ void k_zero(uint4* __restrict__ p, long n){
  long i = (long)blockIdx.x*256 + threadIdx.x;
  if (i < n) p[i] = make_uint4(0,0,0,0);
}

// NCHW x, channel window [icoff, icoff+64*gridDim.y) of batch (bbase+blockIdx.z)
// -> zero-padded NHWC [bi][66][66][ICD]
__global__ void k_pad1(const void* __restrict__ xb, u16* __restrict__ xp, int ICD, int icoff, int bbase,
                       const int* __restrict__ flag){
  __shared__ u16 tile[64][65];
  const int h = blockIdx.x;
  const int ic0 = blockIdx.y<<6;
  const int bi = blockIdx.z;
  const int t = threadIdx.x, lane = t&63, g = t>>6;
  const size_t base = ((size_t)(bbase+bi)*2048 + icoff + ic0)*4096 + (size_t)h*64;
  if (*flag){
    const float* src = (const float*)xb + base;
#pragma unroll
    for(int i=0;i<16;i++){ int icl = g*16+i; tile[icl][lane] = f2bf(src[(size_t)icl*4096 + lane]); }
  } else {
    const u16* src = (const u16*)xb + base;
#pragma unroll
    for(int i=0;i<16;i++){ int icl = g*16+i; tile[icl][lane] = src[(size_t)icl*4096 + lane]; }
  }
  __syncthreads();
  u16* dst = xp + ((size_t)bi*4356 + ((size_t)(h+1))*66 + 1)*ICD + ic0;
#pragma unroll
  for(int j=0;j<16;j++){ int w = g*16+j; dst[(size_t)w*ICD + lane] = tile[lane][w]; }
}

// OIHW 3x3 weights (OC=512, src IC count ICS), ic window [icoff,icoff+ICD) -> [tap][oc][icd]
__global__ void k_wtrans(const void* __restrict__ w, u16* __restrict__ wt, int ICS, int ICD, int icoff,
                         const int* __restrict__ flag){
  size_t i = (size_t)blockIdx.x*256 + threadIdx.x;  // grid sized exactly 9*512*ICD/256
  int icd = (int)(i & (ICD-1));
  size_t rest = i / ICD;
  int oc = (int)(rest & 511);
  int tap = (int)(rest >> 9);
  size_t sidx = ((size_t)oc*ICS + icoff + icd)*9 + tap;
  wt[i] = (*flag) ? f2bf(((const float*)w)[sidx]) : ((const u16*)w)[sidx];
}

// bf16 transpose [R][C] -> [C][R]
__global__ void k_transpose(const u16* __restrict__ in, u16* __restrict__ outp, int R, int C){
  __shared__ u16 tile[64][65];
  const int c0 = blockIdx.x<<6, r0 = blockIdx.y<<6;
  const int t=threadIdx.x, lane=t&63, g=t>>6;
#pragma unroll
  for(int i=0;i<16;i++){ int rl=g*16+i; tile[rl][lane] = in[(size_t)(r0+rl)*C + c0 + lane]; }
  __syncthreads();
#pragma unroll
  for(int j=0;j<16;j++){ int cl=g*16+j; outp[(size_t)(c0+cl)*R + r0 + lane] = tile[lane][cl]; }
}

// NHWC strip [npix][C] -> padded [nb][66][66][C] interior (nb = npix/4096)
__global__ void k_pad_strip(const u16* __restrict__ in, u16* __restrict__ outp, int C, int npix){
  long i = (long)blockIdx.x*256 + threadIdx.x;   // vec8 index
  int vpp = C>>3;
  if (i >= (long)npix*vpp) return;
  int p = (int)(i/vpp), v = (int)(i - (long)p*vpp);
  int b = p>>12, h=(p>>6)&63, w=p&63;
  ((uint4*)outp)[((size_t)(b*66+h+1)*66 + (w+1))*vpp + v] = ((const uint4*)in)[i];
}

__global__ void k_add_bf16(const u16* __restrict__ a, const u16* __restrict__ b, u16* __restrict__ o, long n){
  long i = ((long)blockIdx.x*256 + threadIdx.x)*8;
  if (i >= n) return;
  uint4 va = *(const uint4*)(a+i), vb = *(const uint4*)(b+i);
  u16* pa=(u16*)&va; u16* pb=(u16*)&vb;
  uint4 vo; u16* po=(u16*)&vo;
#pragma unroll
  for(int e=0;e<8;e++) po[e] = f2bf(bf2f(pa[e]) + bf2f(pb[e]));
  *(uint4*)(o+i) = vo;
}

// generic NT GEMM: C[MxN] = A[MxK] * Bt[NxK]^T
// mode 0: bf16 plain; 1: bf16 + bias q1[col]; 3: bf16 alpha(q1[0])*acc + resid q2[idx];
// mode 4: f32 plain; 5: bf16 + bias q1[row].
// zk>0: split-K -- blockIdx.z selects k-window [z*zk, z*zk+zk) and offsets Cout by z*zcb bytes.
__global__ __launch_bounds__(256,2) void gemm_nt(
    const u16* __restrict__ A, const u16* __restrict__ Bt,
    int N, int K, int lda, int ldb,
    void* __restrict__ Cout, int ldc, int mode,
    const u16* __restrict__ q1, const u16* __restrict__ q2, int zk, long zcb)
{
  if (zk){
    const int zz = blockIdx.z;
    A  += (size_t)zz*zk;
    Bt += (size_t)zz*zk;
    Cout = (void*)((char*)Cout + (size_t)zz*zcb);
    K = zk;
  }
  __shared__ __align__(16) u16 As[128*40];
  __shared__ __align__(16) u16 Bs[128*40];
  const int t = threadIdx.x;
  const int m0 = blockIdx.y<<7, n0 = blockIdx.x<<7;
  const int r = t>>2, q = t&3;
  const u16* A0 = A + (size_t)(m0+r)*lda + q*8;
  const u16* A1 = A0 + (size_t)64*lda;
  const bool bv0 = (n0+r)    < N;
  const bool bv1 = (n0+r+64) < N;
  const u16* B0 = Bt + (size_t)(n0+r)*ldb + q*8;
  const u16* B1 = B0 + (size_t)64*ldb;
  const int wave=t>>6, lane=t&63;
  const int wr=(wave>>1)<<6, wc=(wave&1)<<6, fm=lane&15, kg=lane>>4;
  f32x4 acc[4][4] = {};
  for (int k0=0; k0<K; k0+=32){
    uint4 a0 = *(const uint4*)(A0+k0);
    uint4 a1 = *(const uint4*)(A1+k0);
    uint4 b0 = bv0 ? *(const uint4*)(B0+k0) : make_uint4(0,0,0,0);
    uint4 b1 = bv1 ? *(const uint4*)(B1+k0) : make_uint4(0,0,0,0);
    __syncthreads();
    *(uint4*)&As[r*40+q*8] = a0;
    *(uint4*)&As[(r+64)*40+q*8] = a1;
    *(uint4*)&Bs[r*40+q*8] = b0;
    *(uint4*)&Bs[(r+64)*40+q*8] = b1;
    __syncthreads();
    bf16x8 af[4], bfr[4];
#pragma unroll
    for(int i=0;i<4;i++) af[i]  = *(const bf16x8*)&As[(wr+i*16+fm)*40 + kg*8];
#pragma unroll
    for(int j=0;j<4;j++) bfr[j] = *(const bf16x8*)&Bs[(wc+j*16+fm)*40 + kg*8];
#pragma unroll
    for(int i=0;i<4;i++)
#pragma unroll
      for(int j=0;j<4;j++)
        acc[i][j] = __builtin_amdgcn_mfma_f32_16x16x32_bf16(af[i], bfr[j], acc[i][j], 0,0,0);
  }
  const float alpha = (mode==3) ? bf2f(q1[0]) : 0.f;
#pragma unroll
  for(int j=0;j<4;j++){
    int col = n0 + wc + j*16 + fm;
    if (col >= N) continue;
    float bias = (mode==1) ? bf2f(q1[col]) : 0.f;
#pragma unroll
    for(int i=0;i<4;i++){
      int row = m0 + wr + i*16 + (kg<<2);
#pragma unroll
      for(int rr=0;rr<4;rr++){
        long idx = (long)(row+rr)*ldc + col;
        float v = acc[i][j][rr];
        if (mode==4)      ((float*)Cout)[idx] = v;
        else if (mode==3) ((u16*)Cout)[idx] = f2bf(alpha*v + bf2f(q2[idx]));
        else if (mode==5) ((u16*)Cout)[idx] = f2bf(v + bf2f(q1[row+rr]));
        else if (mode==1) ((u16*)Cout)[idx] = f2bf(v + bias);
        else              ((u16*)Cout)[idx] = f2bf(v);
      }
    }
  }
}

// implicit-GEMM 3x3 conv (padded NHWC in, tap-major weights, OC=512)
// phase 0: Out = raw partial (bf16);  1: Out = relu(s*(Out + acc) + b);  2: Out = relu(s*acc + b)
__global__ __launch_bounds__(256,2) void conv3_gemm(
    const u16* __restrict__ Xp, const u16* __restrict__ Wt, int ICt,
    u16* __restrict__ Out, const u16* __restrict__ scale, const u16* __restrict__ bias, int phase)
{
  __shared__ __align__(16) u16 As[128*40];
  __shared__ __align__(16) u16 Bs[128*40];
  const int t = threadIdx.x;
  const int m0 = blockIdx.y<<7, n0 = blockIdx.x<<7;
  const int r = t>>2, q = t&3;
  const int p0 = m0 + r, p1 = p0 + 64;
  const size_t xb0 = ((size_t)((p0>>12)*66 + ((p0>>6)&63))*66 + (p0&63))*ICt + q*8;
  const size_t xb1 = ((size_t)((p1>>12)*66 + ((p1>>6)&63))*66 + (p1&63))*ICt + q*8;
  const u16* W0 = Wt + (size_t)(n0+r)*ICt + q*8;
  const u16* W1 = W0 + (size_t)64*ICt;
  const size_t wtap = (size_t)512*ICt;
  const int wave=t>>6, lane=t&63;
  const int wr=(wave>>1)<<6, wc=(wave&1)<<6, fm=lane&15, kg=lane>>4;
  f32x4 acc[4][4] = {};
  for (int tap=0; tap<9; tap++){
    const size_t toff = (size_t)((tap/3)*66 + (tap%3))*ICt;
    const u16* xa0 = Xp + xb0 + toff;
    const u16* xa1 = Xp + xb1 + toff;
    const u16* wa0 = W0 + (size_t)tap*wtap;
    const u16* wa1 = W1 + (size_t)tap*wtap;
    for (int k0=0; k0<ICt; k0+=32){
      uint4 a0 = *(const uint4*)(xa0+k0);
      uint4 a1 = *(const uint4*)(xa1+k0);
      uint4 b0 = *(const uint4*)(wa0+k0);
      uint4 b1 = *(const uint4*)(wa1+k0);
      __syncthreads();
      *(uint4*)&As[r*40+q*8] = a0;
      *(uint4*)&As[(r+64)*40+q*8] = a1;
      *(uint4*)&Bs[r*40+q*8] = b0;
      *(uint4*)&Bs[(r+64)*40+q*8] = b1;
      __syncthreads();
      bf16x8 af[4], bfr[4];
#pragma unroll
      for(int i=0;i<4;i++) af[i]  = *(const bf16x8*)&As[(wr+i*16+fm)*40 + kg*8];
#pragma unroll
      for(int j=0;j<4;j++) bfr[j] = *(const bf16x8*)&Bs[(wc+j*16+fm)*40 + kg*8];
#pragma unroll
      for(int i=0;i<4;i++)
#pragma unroll
        for(int j=0;j<4;j++)
          acc[i][j] = __builtin_amdgcn_mfma_f32_16x16x32_bf16(af[i], bfr[j], acc[i][j], 0,0,0);
    }
  }
#pragma unroll
  for(int j=0;j<4;j++){
    int col = n0 + wc + j*16 + fm;
    float s = bf2f(scale[col]), bb = bf2f(bias[col]);
#pragma unroll
    for(int i=0;i<4;i++){
      int row = m0 + wr + i*16 + (kg<<2);
#pragma unroll
      for(int rr=0;rr<4;rr++){
        size_t idx = (size_t)(row+rr)*512 + col;
        float v = acc[i][j][rr];
        if (phase == 0)      Out[idx] = f2bf(v);
        else if (phase == 1) Out[idx] = f2bf(fmaxf(s*(bf2f(Out[idx]) + v) + bb, 0.f));
        else                 Out[idx] = f2bf(fmaxf(s*v + bb, 0.f));
      }
    }
  }
}

// PAM row softmax, in-place over rows of 4096 bf16
__global__ __launch_bounds__(256) void k_softmax_pam(u16* __restrict__ attn){
  __shared__ float red[8];
  u16* row = attn + (size_t)blockIdx.x*4096;
  uint4* rv = (uint4*)row;
  const int t = threadIdx.x;
  uint4 c0 = rv[2*t], c1 = rv[2*t+1];
  u16* e0 = (u16*)&c0; u16* e1=(u16*)&c1;
  float v[16];
#pragma unroll
  for(int i=0;i<8;i++){ v[i]=bf2f(e0[i]); v[8+i]=bf2f(e1[i]); }
  float mx = v[0];
#pragma unroll
  for(int i=1;i<16;i++) mx = fmaxf(mx, v[i]);
  mx = wave_max(mx);
  if((t&63)==0) red[t>>6] = mx;
  __syncthreads();
  mx = fmaxf(fmaxf(red[0],red[1]),fmaxf(red[2],red[3]));
  float s = 0.f;
#pragma unroll
  for(int i=0;i<16;i++){ v[i]=__expf(v[i]-mx); s += v[i]; }
  s = wave_sum(s);
  if((t&63)==0) red[4+(t>>6)] = s;
  __syncthreads();
  s = red[4]+red[5]+red[6]+red[7];
  float inv = 1.f/s;
#pragma unroll
  for(int i=0;i<8;i++){ e0[i]=f2bf(v[i]*inv); e1[i]=f2bf(v[8+i]*inv); }
  rv[2*t]=c0; rv[2*t+1]=c1;
}

// PV split-K combine: io = f2bf(alpha * (P0+P1+P2+P3) + io)   (4 splits of 2048x512 f32)
__global__ __launch_bounds__(256) void k_pv_combine(const float* __restrict__ Pp, u16* __restrict__ io,
                                                    const u16* __restrict__ alpha){
  const int i = blockIdx.x*256 + threadIdx.x;     // float4 index, 262144 total
  const float4* p = (const float4*)Pp;
  float4 a0 = p[i], a1 = p[i+262144], a2 = p[i+524288], a3 = p[i+786432];
  const float al = bf2f(alpha[0]);
  ushort4 d = ((const ushort4*)io)[i];
  ushort4 o;
  o.x = f2bf(al*(a0.x+a1.x+a2.x+a3.x) + bf2f(d.x));
  o.y = f2bf(al*(a0.y+a1.y+a2.y+a3.y) + bf2f(d.y));
  o.z = f2bf(al*(a0.z+a1.z+a2.z+a3.z) + bf2f(d.z));
  o.w = f2bf(al*(a0.w+a1.w+a2.w+a3.w) + bf2f(d.w));
  ((ushort4*)io)[i] = o;
}

// CAM softmax over split-K partial sums: out[c][d] = softmax_d(-(P0+P1+P2+P3))
__global__ __launch_bounds__(256) void k_softmax_cam4(const float* __restrict__ P4, u16* __restrict__ outp){
  __shared__ float red[8];
  const int t = threadIdx.x;
  const float* r0 = P4 + (size_t)blockIdx.x*512;  // split stride 262144 floats (512x512)
  float a  = -(r0[t]     + r0[262144+t]     + r0[524288+t]     + r0[786432+t]);
  float b2 = -(r0[256+t] + r0[262144+256+t] + r0[524288+256+t] + r0[786432+256+t]);
  float mx = wave_max(fmaxf(a,b2));
  if((t&63)==0) red[t>>6]=mx;
  __syncthreads();
  mx = fmaxf(fmaxf(red[0],red[1]),fmaxf(red[2],red[3]));
  float ea = __expf(a-mx), eb = __expf(b2-mx);
  float s = wave_sum(ea+eb);
  if((t&63)==0) red[4+(t>>6)]=s;
  __syncthreads();
  s = red[4]+red[5]+red[6]+red[7];
  float inv = 1.f/s;
  u16* orow = outp + (size_t)blockIdx.x*512;
  orow[t] = f2bf(ea*inv); orow[t+256] = f2bf(eb*inv);
}

// bilinear 2x upsample (half-pixel, clamp), NHWC[16384][81] -> NCHW out (f32 or bf16 per flag)
__global__ __launch_bounds__(128) void k_upsample(const u16* __restrict__ hp, const u16* __restrict__ hc,
                                                  const u16* __restrict__ hf, void* __restrict__ outp,
                                                  const int* __restrict__ flag){
  int bx = blockIdx.x;
  const int y = bx & 127; bx >>= 7;
  const int ch = bx % 81; bx /= 81;
  const int b = bx & 3; const int head = bx >> 2;
  const u16* src = (head==0) ? hp : (head==1 ? hc : hf);
  const int xo = threadIdx.x;
  float fy = y*0.5f - 0.25f, fx = xo*0.5f - 0.25f;
  float fy0 = floorf(fy), fx0 = floorf(fx);
  float wy = fy - fy0, wx = fx - fx0;
  int y0 = max((int)fy0, 0), y1 = min((int)fy0 + 1, 63);
  int x0 = max((int)fx0, 0), x1 = min((int)fx0 + 1, 63);
  const size_t bb = (size_t)b*4096;
  float v00 = bf2f(src[(bb + y0*64 + x0)*81 + ch]);
  float v01 = bf2f(src[(bb + y0*64 + x1)*81 + ch]);
  float v10 = bf2f(src[(bb + y1*64 + x0)*81 + ch]);
  float v11 = bf2f(src[(bb + y1*64 + x1)*81 + ch]);
  float v = (1.f-wy)*((1.f-wx)*v00 + wx*v01) + wy*((1.f-wx)*v10 + wx*v11);
  size_t oidx = ((size_t)(head*324 + b*81 + ch))*16384 + (size_t)y*128 + xo;
  if (*flag) ((float*)outp)[oidx] = v;
  else       ((u16*)outp)[oidx]  = f2bf(v);
}

extern "C" void kernel_launch(void* const* d_in, const int* in_sizes, int n_in,
                              void* d_out, int out_size, void* d_ws, size_t ws_size,
                              hipStream_t stream)
{
  (void)in_sizes; (void)n_in;
  const void* x   = d_in[0];
  const void* wp1 = d_in[1];
  const void* wc1 = d_in[4];
  const void* wp2 = d_in[15];
  const void* wc2 = d_in[18];
  char* ws = (char*)d_ws;
  const size_t MB = 1048576;
  auto P = [&](size_t off){ return (u16*)(ws + off); };

  // ws probe: plan needs 58 MiB of workspace.
  // d_out is used as scratch; out_size is an ELEMENT count (harness reads (out_size,) array).
  // Worst-case capacity = out_size*2 bytes (bf16 output); we need 18 MiB of scratch.
  if (ws_size < 58*MB || (long)out_size*2 < (long)18*MB){
    k_sentinel<<<1,1,0,stream>>>((u16*)d_out, 16.0f * (float)(ws_size / MB));
    return;
  }

  // ws regions (MiB offsets; params region [56,58) never aliased):
  //  conv1: FP1 [0,16) FC1 [16,32) WTCP [32,41) WTCC [41,50)      (padded x chunk lives in d_out, 17.9MB)
  //  PAM:   FB [32,34) FCc [34,36) FDTb [36,40) PV-partials [40,56)  (ATTN chunk in d_out, 16MB)
  //  CAM:   FATb [32,36) Gram-partials [36,40) FEATC [40,56)       (ATTCS in d_out, 0.5MB)
  //  conv2: WT2P [16,20.5) WT2C [20.5,25)                          (padded strip in d_out, 17.9MB)
  //  heads: FUS [16,32) HP [32,35) HC [35,38) HF [38,40.6) -- HF clobbers FEATC head AFTER HC gemm
  const size_t FP1=0, FC1=16*MB, WTCP=32*MB, WTCC=41*MB,
               FB=32*MB, FCc=34*MB, FDTb=36*MB, PP=40*MB,
               FATb=32*MB, CP=36*MB, FEATC=40*MB,
               WT2P=16*MB, WT2C=WT2P+4718592,
               FUS=16*MB, HP=32*MB, HC=35*MB, HF=38*MB;
  u16* prm = P(56*MB);
  int* FLAG = (int*)(ws + 57*MB + 524288);
  u16* SCR = (u16*)d_out;   // d_out used as scratch; fully overwritten by k_upsample at the end
  const int SP1=0, BP1=512, SC1=1024, BC1=1536, SP2=2048, BP2=2560, SC2=3072, BC2=3584,
            PBB=4096, PBC=4160, PBD=4224, BP3=4736, BC3=4817, BLOG=4898, ALPHA=4979, BETA=4980,
            PWB=4992, PWC=37760, PWD=70528, W3P=332672, W3C=374144, W3L=415616;

  // ---- dtype probe + param normalization to bf16 ----
  k_probe<<<1, 256, 0, stream>>>((const unsigned*)x, FLAG);
  auto cv = [&](int di, int po, int n){
    k_cvt<<<(n+255)/256, 256, 0, stream>>>(d_in[di], prm+po, n, FLAG);
  };
  cv(2,SP1,512);  cv(3,BP1,512);  cv(5,SC1,512);  cv(6,BC1,512);
  cv(16,SP2,512); cv(17,BP2,512); cv(19,SC2,512); cv(20,BC2,512);
  cv(8,PBB,64);   cv(10,PBC,64);  cv(12,PBD,512);
  cv(24,BP3,81);  cv(26,BC3,81);  cv(22,BLOG,81);
  cv(13,ALPHA,1); cv(14,BETA,1);
  cv(7,PWB,32768); cv(9,PWC,32768); cv(11,PWD,262144);
  cv(23,W3P,41472); cv(25,W3C,41472); cv(21,W3L,41472);

  // ---- conv1 (2048->512), 2 ic-chunks of 1024, 2 batches per dispatch ----
  // 2-batch padded chunk = 2*66*66*1024*2B = 17.9 MB, fits worst-case d_out capacity (31.8 MB).
  const int BPD = 2;
  const int nbp = 4/BPD;
  k_zero<<<BPD*2178, 256, 0, stream>>>((uint4*)SCR, (long)BPD*557568);  // BPD*66*66*1024 bf16
  for (int ch=0; ch<2; ch++){
    k_wtrans<<<18432, 256, 0, stream>>>(wp1, P(WTCP), 2048, 1024, ch*1024, FLAG);
    k_wtrans<<<18432, 256, 0, stream>>>(wc1, P(WTCC), 2048, 1024, ch*1024, FLAG);
    for (int bp=0; bp<nbp; bp++){
      k_pad1<<<dim3(64,16,BPD), 256, 0, stream>>>(x, SCR, 1024, ch*1024, bp*BPD, FLAG);
      const size_t ob = (size_t)bp*BPD*4096*512;
      conv3_gemm<<<dim3(4,32*BPD), 256, 0, stream>>>(SCR, P(WTCP), 1024, P(FP1)+ob, prm+SP1, prm+BP1, ch);
      conv3_gemm<<<dim3(4,32*BPD), 256, 0, stream>>>(SCR, P(WTCC), 1024, P(FC1)+ob, prm+SC1, prm+BC1, ch);
    }
  }

  // ---- PAM (writes feat_p in-place over FP1) ----
  gemm_nt<<<dim3(1,128), 256, 0, stream>>>(P(FP1), prm+PWB, 64, 512, 512, 512, P(FB), 64, 1, prm+PBB, nullptr, 0, 0);
  gemm_nt<<<dim3(1,128), 256, 0, stream>>>(P(FP1), prm+PWC, 64, 512, 512, 512, P(FCc), 64, 1, prm+PBC, nullptr, 0, 0);
  for (int b=0;b<4;b++){
    const size_t fo = (size_t)b*4096*64, so = (size_t)b*4096*512;
    // FD^T directly: C[c][m] = sum_ic wd[c][ic]*feat_p[m][ic] + bd[c]  (mode 5 = row bias)
    gemm_nt<<<dim3(32,4), 256, 0, stream>>>(prm+PWD, P(FP1)+so, 4096, 512, 512, 512, P(FDTb), 4096, 5, prm+PBD, nullptr, 0, 0);
    for (int ck=0;ck<2;ck++){
      // attn chunk [2048][4096] in d_out
      gemm_nt<<<dim3(32,16), 256, 0, stream>>>(P(FB)+fo+(size_t)ck*131072, P(FCc)+fo, 4096, 64, 64, 64, SCR, 4096, 0, nullptr, nullptr, 0, 0);
      k_softmax_pam<<<2048, 256, 0, stream>>>(SCR);
      // PV split-K=4 into f32 partials, then combine with alpha + residual (in-place FP1)
      gemm_nt<<<dim3(4,16,4), 256, 0, stream>>>(SCR, P(FDTb), 512, 4096, 4096, 4096, (void*)P(PP), 512, 4, nullptr, nullptr, 1024, 4194304);
      k_pv_combine<<<1024, 256, 0, stream>>>((const float*)P(PP), P(FP1)+so+(size_t)ck*1048576, prm+ALPHA);
    }
  }

  // ---- CAM (per-batch; FEATC separate buffer; Gram matrix split-K=4) ----
  for (int b=0;b<4;b++){
    const size_t so = (size_t)b*4096*512;
    k_transpose<<<dim3(8,64), 256, 0, stream>>>(P(FC1)+so, P(FATb), 4096, 512);
    gemm_nt<<<dim3(4,4,4), 256, 0, stream>>>(P(FATb), P(FATb), 512, 4096, 4096, 4096, (void*)P(CP), 512, 4, nullptr, nullptr, 1024, 1048576);
    k_softmax_cam4<<<512, 256, 0, stream>>>((const float*)P(CP), SCR);
    gemm_nt<<<dim3(4,32), 256, 0, stream>>>(P(FC1)+so, SCR, 512, 512, 512, 512, P(FEATC)+so, 512, 3, prm+BETA, P(FC1)+so, 0, 0);
  }

  // ---- conv2 pair (all-batch padded strip in d_out, in-place over FP1 / FEATC) ----
  k_wtrans<<<9216, 256, 0, stream>>>(wp2, P(WT2P), 512, 512, 0, FLAG);
  k_wtrans<<<9216, 256, 0, stream>>>(wc2, P(WT2C), 512, 512, 0, FLAG);
  k_zero<<<4356, 256, 0, stream>>>((uint4*)SCR, 1115136);  // 4*66*66*512 bf16
  k_pad_strip<<<4096, 256, 0, stream>>>(P(FP1), SCR, 512, 16384);
  conv3_gemm<<<dim3(4,128), 256, 0, stream>>>(SCR, P(WT2P), 512, P(FP1), prm+SP2, prm+BP2, 2);
  k_pad_strip<<<4096, 256, 0, stream>>>(P(FEATC), SCR, 512, 16384);
  conv3_gemm<<<dim3(4,128), 256, 0, stream>>>(SCR, P(WT2C), 512, P(FEATC), prm+SC2, prm+BC2, 2);

  // ---- heads + upsample ----
  k_add_bf16<<<4096, 256, 0, stream>>>(P(FP1), P(FEATC), P(FUS), (long)16384*512);
  gemm_nt<<<dim3(1,128), 256, 0, stream>>>(P(FP1), prm+W3P, 81, 512, 512, 512, P(HP), 81, 1, prm+BP3, nullptr, 0, 0);
  gemm_nt<<<dim3(1,128), 256, 0, stream>>>(P(FEATC), prm+W3C, 81, 512, 512, 512, P(HC), 81, 1, prm+BC3, nullptr, 0, 0);
  // HF region overlaps FEATC's first MiBs -- must run after HC gemm (stream-ordered).
  gemm_nt<<<dim3(1,128), 256, 0, stream>>>(P(FUS), prm+W3L, 81, 512, 512, 512, P(HF), 81, 1, prm+BLOG, nullptr, 0, 0);
  k_upsample<<<124416, 128, 0, stream>>>(P(HP), P(HC), P(HF), d_out, FLAG);
}

// Round 4
// 2473.855 us; speedup vs baseline: 2.5134x; 1.2487x over previous
//
#include <hip/hip_runtime.h>

typedef unsigned short u16;
typedef __bf16 bf16x8 __attribute__((ext_vector_type(8)));
typedef float f32x4 __attribute__((ext_vector_type(4)));

static __device__ __forceinline__ float bf2f(u16 v){ unsigned u=((unsigned)v)<<16; float f; __builtin_memcpy(&f,&u,4); return f; }
static __device__ __forceinline__ u16 f2bf(float f){ unsigned u; __builtin_memcpy(&u,&f,4); u += 0x7fffu + ((u>>16)&1u); return (u16)(u>>16); }

static __device__ __forceinline__ float wave_max(float v){
#pragma unroll
  for(int o=32;o;o>>=1) v=fmaxf(v,__shfl_xor(v,o,64));
  return v;
}
static __device__ __forceinline__ float wave_sum(float v){
#pragma unroll
  for(int o=32;o;o>>=1) v+=__shfl_xor(v,o,64);
  return v;
}

__global__ void k_sentinel(u16* __restrict__ o, float v){ o[0] = f2bf(v); }

// dtype probe: if any u16 half of x's first 32768 words has exponent field 0xFF,
// the data cannot be finite bf16 -> it is f32 mantissa bits. flag=1 => f32 inputs.
__global__ void k_probe(const unsigned* __restrict__ w, int* __restrict__ flag){
  __shared__ int found;
  if (threadIdx.x==0) found = 0;
  __syncthreads();
  int loc = 0;
  for (int i = threadIdx.x; i < 32768; i += 256){
    unsigned v = w[i];
    if ((((v >> 7) & 0xFFu) == 0xFFu) || (((v >> 23) & 0xFFu) == 0xFFu)) loc = 1;
  }
  if (loc) atomicOr(&found, 1);
  __syncthreads();
  if (threadIdx.x==0) *flag = found;
}

// normalize a tensor to bf16 (identity copy if already bf16)
__global__ void k_cvt(const void* __restrict__ src, u16* __restrict__ dst, int n, const int* __restrict__ flag){
  int i = blockIdx.x*256 + threadIdx.x;
  if (i >= n) return;
  if (*flag) dst[i] = f2bf(((const float*)src)[i]);
  else       dst[i] = ((const u16*)src)[i];
}

__global__ void k_zero(uint4* __restrict__ p, long n){
  long i = (long)blockIdx.x*256 + threadIdx.x;
  if (i < n) p[i] = make_uint4(0,0,0,0);
}

// NCHW x, channel window [icoff, icoff+64*gridDim.y) of batch (bbase+blockIdx.z)
// -> zero-padded NHWC [bi][66][66][ICD]
__global__ void k_pad1(const void* __restrict__ xb, u16* __restrict__ xp, int ICD, int icoff, int bbase,
                       const int* __restrict__ flag){
  __shared__ u16 tile[64][65];
  const int h = blockIdx.x;
  const int ic0 = blockIdx.y<<6;
  const int bi = blockIdx.z;
  const int t = threadIdx.x, lane = t&63, g = t>>6;
  const size_t base = ((size_t)(bbase+bi)*2048 + icoff + ic0)*4096 + (size_t)h*64;
  if (*flag){
    const float* src = (const float*)xb + base;
#pragma unroll
    for(int i=0;i<16;i++){ int icl = g*16+i; tile[icl][lane] = f2bf(src[(size_t)icl*4096 + lane]); }
  } else {
    const u16* src = (const u16*)xb + base;
#pragma unroll
    for(int i=0;i<16;i++){ int icl = g*16+i; tile[icl][lane] = src[(size_t)icl*4096 + lane]; }
  }
  __syncthreads();
  u16* dst = xp + ((size_t)bi*4356 + ((size_t)(h+1))*66 + 1)*ICD + ic0;
#pragma unroll
  for(int j=0;j<16;j++){ int w = g*16+j; dst[(size_t)w*ICD + lane] = tile[lane][w]; }
}

// OIHW 3x3 weights (OC=512, src IC count ICS), ic window [icoff,icoff+ICD) -> [tap][oc][icd]
__global__ void k_wtrans(const void* __restrict__ w, u16* __restrict__ wt, int ICS, int ICD, int icoff,
                         const int* __restrict__ flag){
  size_t i = (size_t)blockIdx.x*256 + threadIdx.x;  // grid sized exactly 9*512*ICD/256
  int icd = (int)(i & (ICD-1));
  size_t rest = i / ICD;
  int oc = (int)(rest & 511);
  int tap = (int)(rest >> 9);
  size_t sidx = ((size_t)oc*ICS + icoff + icd)*9 + tap;
  wt[i] = (*flag) ? f2bf(((const float*)w)[sidx]) : ((const u16*)w)[sidx];
}

// bf16 transpose [R][C] -> [C][R]
__global__ void k_transpose(const u16* __restrict__ in, u16* __restrict__ outp, int R, int C){
  __shared__ u16 tile[64][65];
  const int c0 = blockIdx.x<<6, r0 = blockIdx.y<<6;
  const int t=threadIdx.x, lane=t&63, g=t>>6;
#pragma unroll
  for(int i=0;i<16;i++){ int rl=g*16+i; tile[rl][lane] = in[(size_t)(r0+rl)*C + c0 + lane]; }
  __syncthreads();
#pragma unroll
  for(int j=0;j<16;j++){ int cl=g*16+j; outp[(size_t)(c0+cl)*R + r0 + lane] = tile[lane][cl]; }
}

// NHWC strip [npix][C] -> padded [nb][66][66][C] interior (nb = npix/4096)
__global__ void k_pad_strip(const u16* __restrict__ in, u16* __restrict__ outp, int C, int npix){
  long i = (long)blockIdx.x*256 + threadIdx.x;   // vec8 index
  int vpp = C>>3;
  if (i >= (long)npix*vpp) return;
  int p = (int)(i/vpp), v = (int)(i - (long)p*vpp);
  int b = p>>12, h=(p>>6)&63, w=p&63;
  ((uint4*)outp)[((size_t)(b*66+h+1)*66 + (w+1))*vpp + v] = ((const uint4*)in)[i];
}

__global__ void k_add_bf16(const u16* __restrict__ a, const u16* __restrict__ b, u16* __restrict__ o, long n){
  long i = ((long)blockIdx.x*256 + threadIdx.x)*8;
  if (i >= n) return;
  uint4 va = *(const uint4*)(a+i), vb = *(const uint4*)(b+i);
  u16* pa=(u16*)&va; u16* pb=(u16*)&vb;
  uint4 vo; u16* po=(u16*)&vo;
#pragma unroll
  for(int e=0;e<8;e++) po[e] = f2bf(bf2f(pa[e]) + bf2f(pb[e]));
  *(uint4*)(o+i) = vo;
}

// generic NT GEMM: C[MxN] = A[MxK] * Bt[NxK]^T
// mode 0: bf16 plain; 1: bf16 + bias q1[col]; 3: bf16 alpha(q1[0])*acc + resid q2[idx];
// mode 4: f32 plain; 5: bf16 + bias q1[row].
// zk>0: split-K -- blockIdx.z selects k-window [z*zk, z*zk+zk) and offsets Cout by z*zcb bytes.
__global__ __launch_bounds__(256,2) void gemm_nt(
    const u16* __restrict__ A, const u16* __restrict__ Bt,
    int N, int K, int lda, int ldb,
    void* __restrict__ Cout, int ldc, int mode,
    const u16* __restrict__ q1, const u16* __restrict__ q2, int zk, long zcb)
{
  if (zk){
    const int zz = blockIdx.z;
    A  += (size_t)zz*zk;
    Bt += (size_t)zz*zk;
    Cout = (void*)((char*)Cout + (size_t)zz*zcb);
    K = zk;
  }
  __shared__ __align__(16) u16 As[128*40];
  __shared__ __align__(16) u16 Bs[128*40];
  const int t = threadIdx.x;
  const int m0 = blockIdx.y<<7, n0 = blockIdx.x<<7;
  const int r = t>>2, q = t&3;
  const u16* A0 = A + (size_t)(m0+r)*lda + q*8;
  const u16* A1 = A0 + (size_t)64*lda;
  const bool bv0 = (n0+r)    < N;
  const bool bv1 = (n0+r+64) < N;
  const u16* B0 = Bt + (size_t)(n0+r)*ldb + q*8;
  const u16* B1 = B0 + (size_t)64*ldb;
  const int wave=t>>6, lane=t&63;
  const int wr=(wave>>1)<<6, wc=(wave&1)<<6, fm=lane&15, kg=lane>>4;
  f32x4 acc[4][4] = {};
  for (int k0=0; k0<K; k0+=32){
    uint4 a0 = *(const uint4*)(A0+k0);
    uint4 a1 = *(const uint4*)(A1+k0);
    uint4 b0 = bv0 ? *(const uint4*)(B0+k0) : make_uint4(0,0,0,0);
    uint4 b1 = bv1 ? *(const uint4*)(B1+k0) : make_uint4(0,0,0,0);
    __syncthreads();
    *(uint4*)&As[r*40+q*8] = a0;
    *(uint4*)&As[(r+64)*40+q*8] = a1;
    *(uint4*)&Bs[r*40+q*8] = b0;
    *(uint4*)&Bs[(r+64)*40+q*8] = b1;
    __syncthreads();
    bf16x8 af[4], bfr[4];
#pragma unroll
    for(int i=0;i<4;i++) af[i]  = *(const bf16x8*)&As[(wr+i*16+fm)*40 + kg*8];
#pragma unroll
    for(int j=0;j<4;j++) bfr[j] = *(const bf16x8*)&Bs[(wc+j*16+fm)*40 + kg*8];
#pragma unroll
    for(int i=0;i<4;i++)
#pragma unroll
      for(int j=0;j<4;j++)
        acc[i][j] = __builtin_amdgcn_mfma_f32_16x16x32_bf16(af[i], bfr[j], acc[i][j], 0,0,0);
  }
  const float alpha = (mode==3) ? bf2f(q1[0]) : 0.f;
#pragma unroll
  for(int j=0;j<4;j++){
    int col = n0 + wc + j*16 + fm;
    if (col >= N) continue;
    float bias = (mode==1) ? bf2f(q1[col]) : 0.f;
#pragma unroll
    for(int i=0;i<4;i++){
      int row = m0 + wr + i*16 + (kg<<2);
#pragma unroll
      for(int rr=0;rr<4;rr++){
        long idx = (long)(row+rr)*ldc + col;
        float v = acc[i][j][rr];
        if (mode==4)      ((float*)Cout)[idx] = v;
        else if (mode==3) ((u16*)Cout)[idx] = f2bf(alpha*v + bf2f(q2[idx]));
        else if (mode==5) ((u16*)Cout)[idx] = f2bf(v + bf2f(q1[row+rr]));
        else if (mode==1) ((u16*)Cout)[idx] = f2bf(v + bias);
        else              ((u16*)Cout)[idx] = f2bf(v);
      }
    }
  }
}

// implicit-GEMM 3x3 conv (padded NHWC in, tap-major weights, OC=512)
// gridDim.x = 4*NBR: low 2 bits = n-panel, upper bits = branch (weight/out/scale/bias strided).
// Branch folding doubles grid occupancy and shares the padded-X read between branches;
// with id%8 XCD round-robin each XCD sees one (panel,branch) weight slab (2.36MB < 4MB L2).
// phase 0: Out = raw partial (bf16);  1: Out = relu(s*(Out + acc) + b);  2: Out = relu(s*acc + b)
__global__ __launch_bounds__(256,2) void conv3_gemm(
    const u16* __restrict__ Xp, const u16* __restrict__ Wt, int ICt,
    u16* __restrict__ Out, const u16* __restrict__ scale, const u16* __restrict__ bias, int phase,
    long wstr, long ostr)
{
  __shared__ __align__(16) u16 As[128*40];
  __shared__ __align__(16) u16 Bs[128*40];
  const int t = threadIdx.x;
  const int bx = blockIdx.x;
  const int brn = bx>>2;
  const int m0 = blockIdx.y<<7, n0 = (bx&3)<<7;
  const u16* Wb = Wt + (size_t)brn*wstr;
  u16* Ob = Out + (size_t)brn*ostr;
  const u16* scb = scale + brn*1024;
  const u16* bib = bias + brn*1024;
  const int r = t>>2, q = t&3;
  const int p0 = m0 + r, p1 = p0 + 64;
  const size_t xb0 = ((size_t)((p0>>12)*66 + ((p0>>6)&63))*66 + (p0&63))*ICt + q*8;
  const size_t xb1 = ((size_t)((p1>>12)*66 + ((p1>>6)&63))*66 + (p1&63))*ICt + q*8;
  const u16* W0 = Wb + (size_t)(n0+r)*ICt + q*8;
  const u16* W1 = W0 + (size_t)64*ICt;
  const size_t wtap = (size_t)512*ICt;
  const int wave=t>>6, lane=t&63;
  const int wr=(wave>>1)<<6, wc=(wave&1)<<6, fm=lane&15, kg=lane>>4;
  f32x4 acc[4][4] = {};
  for (int tap=0; tap<9; tap++){
    const size_t toff = (size_t)((tap/3)*66 + (tap%3))*ICt;
    const u16* xa0 = Xp + xb0 + toff;
    const u16* xa1 = Xp + xb1 + toff;
    const u16* wa0 = W0 + (size_t)tap*wtap;
    const u16* wa1 = W1 + (size_t)tap*wtap;
    for (int k0=0; k0<ICt; k0+=32){
      uint4 a0 = *(const uint4*)(xa0+k0);
      uint4 a1 = *(const uint4*)(xa1+k0);
      uint4 b0 = *(const uint4*)(wa0+k0);
      uint4 b1 = *(const uint4*)(wa1+k0);
      __syncthreads();
      *(uint4*)&As[r*40+q*8] = a0;
      *(uint4*)&As[(r+64)*40+q*8] = a1;
      *(uint4*)&Bs[r*40+q*8] = b0;
      *(uint4*)&Bs[(r+64)*40+q*8] = b1;
      __syncthreads();
      bf16x8 af[4], bfr[4];
#pragma unroll
      for(int i=0;i<4;i++) af[i]  = *(const bf16x8*)&As[(wr+i*16+fm)*40 + kg*8];
#pragma unroll
      for(int j=0;j<4;j++) bfr[j] = *(const bf16x8*)&Bs[(wc+j*16+fm)*40 + kg*8];
#pragma unroll
      for(int i=0;i<4;i++)
#pragma unroll
        for(int j=0;j<4;j++)
          acc[i][j] = __builtin_amdgcn_mfma_f32_16x16x32_bf16(af[i], bfr[j], acc[i][j], 0,0,0);
    }
  }
#pragma unroll
  for(int j=0;j<4;j++){
    int col = n0 + wc + j*16 + fm;
    float s = bf2f(scb[col]), bb = bf2f(bib[col]);
#pragma unroll
    for(int i=0;i<4;i++){
      int row = m0 + wr + i*16 + (kg<<2);
#pragma unroll
      for(int rr=0;rr<4;rr++){
        size_t idx = (size_t)(row+rr)*512 + col;
        float v = acc[i][j][rr];
        if (phase == 0)      Ob[idx] = f2bf(v);
        else if (phase == 1) Ob[idx] = f2bf(fmaxf(s*(bf2f(Ob[idx]) + v) + bb, 0.f));
        else                 Ob[idx] = f2bf(fmaxf(s*v + bb, 0.f));
      }
    }
  }
}

// PAM row softmax, in-place over rows of 4096 bf16
__global__ __launch_bounds__(256) void k_softmax_pam(u16* __restrict__ attn){
  __shared__ float red[8];
  u16* row = attn + (size_t)blockIdx.x*4096;
  uint4* rv = (uint4*)row;
  const int t = threadIdx.x;
  uint4 c0 = rv[2*t], c1 = rv[2*t+1];
  u16* e0 = (u16*)&c0; u16* e1=(u16*)&c1;
  float v[16];
#pragma unroll
  for(int i=0;i<8;i++){ v[i]=bf2f(e0[i]); v[8+i]=bf2f(e1[i]); }
  float mx = v[0];
#pragma unroll
  for(int i=1;i<16;i++) mx = fmaxf(mx, v[i]);
  mx = wave_max(mx);
  if((t&63)==0) red[t>>6] = mx;
  __syncthreads();
  mx = fmaxf(fmaxf(red[0],red[1]),fmaxf(red[2],red[3]));
  float s = 0.f;
#pragma unroll
  for(int i=0;i<16;i++){ v[i]=__expf(v[i]-mx); s += v[i]; }
  s = wave_sum(s);
  if((t&63)==0) red[4+(t>>6)] = s;
  __syncthreads();
  s = red[4]+red[5]+red[6]+red[7];
  float inv = 1.f/s;
#pragma unroll
  for(int i=0;i<8;i++){ e0[i]=f2bf(v[i]*inv); e1[i]=f2bf(v[8+i]*inv); }
  rv[2*t]=c0; rv[2*t+1]=c1;
}

// PV split-K combine: io = f2bf(alpha * (P0+P1+P2+P3) + io)   (4 splits of 2048x512 f32)
__global__ __launch_bounds__(256) void k_pv_combine(const float* __restrict__ Pp, u16* __restrict__ io,
                                                    const u16* __restrict__ alpha){
  const int i = blockIdx.x*256 + threadIdx.x;     // float4 index, 262144 total
  const float4* p = (const float4*)Pp;
  float4 a0 = p[i], a1 = p[i+262144], a2 = p[i+524288], a3 = p[i+786432];
  const float al = bf2f(alpha[0]);
  ushort4 d = ((const ushort4*)io)[i];
  ushort4 o;
  o.x = f2bf(al*(a0.x+a1.x+a2.x+a3.x) + bf2f(d.x));
  o.y = f2bf(al*(a0.y+a1.y+a2.y+a3.y) + bf2f(d.y));
  o.z = f2bf(al*(a0.z+a1.z+a2.z+a3.z) + bf2f(d.z));
  o.w = f2bf(al*(a0.w+a1.w+a2.w+a3.w) + bf2f(d.w));
  ((ushort4*)io)[i] = o;
}

// CAM softmax over split-K partial sums: out[c][d] = softmax_d(-(sum of 8 partials))
__global__ __launch_bounds__(256) void k_softmax_cam8(const float* __restrict__ P8, u16* __restrict__ outp){
  __shared__ float red[8];
  const int t = threadIdx.x;
  const float* r0 = P8 + (size_t)blockIdx.x*512;  // split stride 262144 floats (512x512)
  float a = 0.f, b2 = 0.f;
#pragma unroll
  for(int s2=0;s2<8;s2++){ a += r0[(size_t)s2*262144 + t]; b2 += r0[(size_t)s2*262144 + 256 + t]; }
  a = -a; b2 = -b2;
  float mx = wave_max(fmaxf(a,b2));
  if((t&63)==0) red[t>>6]=mx;
  __syncthreads();
  mx = fmaxf(fmaxf(red[0],red[1]),fmaxf(red[2],red[3]));
  float ea = __expf(a-mx), eb = __expf(b2-mx);
  float s = wave_sum(ea+eb);
  if((t&63)==0) red[4+(t>>6)]=s;
  __syncthreads();
  s = red[4]+red[5]+red[6]+red[7];
  float inv = 1.f/s;
  u16* orow = outp + (size_t)blockIdx.x*512;
  orow[t] = f2bf(ea*inv); orow[t+256] = f2bf(eb*inv);
}

// bilinear 2x upsample (half-pixel, clamp), NHWC[16384][81] -> NCHW out (f32 or bf16 per flag)
__global__ __launch_bounds__(128) void k_upsample(const u16* __restrict__ hp, const u16* __restrict__ hc,
                                                  const u16* __restrict__ hf, void* __restrict__ outp,
                                                  const int* __restrict__ flag){
  int bx = blockIdx.x;
  const int y = bx & 127; bx >>= 7;
  const int ch = bx % 81; bx /= 81;
  const int b = bx & 3; const int head = bx >> 2;
  const u16* src = (head==0) ? hp : (head==1 ? hc : hf);
  const int xo = threadIdx.x;
  float fy = y*0.5f - 0.25f, fx = xo*0.5f - 0.25f;
  float fy0 = floorf(fy), fx0 = floorf(fx);
  float wy = fy - fy0, wx = fx - fx0;
  int y0 = max((int)fy0, 0), y1 = min((int)fy0 + 1, 63);
  int x0 = max((int)fx0, 0), x1 = min((int)fx0 + 1, 63);
  const size_t bb = (size_t)b*4096;
  float v00 = bf2f(src[(bb + y0*64 + x0)*81 + ch]);
  float v01 = bf2f(src[(bb + y0*64 + x1)*81 + ch]);
  float v10 = bf2f(src[(bb + y1*64 + x0)*81 + ch]);
  float v11 = bf2f(src[(bb + y1*64 + x1)*81 + ch]);
  float v = (1.f-wy)*((1.f-wx)*v00 + wx*v01) + wy*((1.f-wx)*v10 + wx*v11);
  size_t oidx = ((size_t)(head*324 + b*81 + ch))*16384 + (size_t)y*128 + xo;
  if (*flag) ((float*)outp)[oidx] = v;
  else       ((u16*)outp)[oidx]  = f2bf(v);
}

extern "C" void kernel_launch(void* const* d_in, const int* in_sizes, int n_in,
                              void* d_out, int out_size, void* d_ws, size_t ws_size,
                              hipStream_t stream)
{
  (void)in_sizes; (void)n_in;
  const void* x   = d_in[0];
  const void* wp1 = d_in[1];
  const void* wc1 = d_in[4];
  const void* wp2 = d_in[15];
  const void* wc2 = d_in[18];
  char* ws = (char*)d_ws;
  const size_t MB = 1048576;
  auto P = [&](size_t off){ return (u16*)(ws + off); };

  // ws probe: plan needs 58 MiB of workspace.
  // d_out is used as scratch; out_size is an ELEMENT count. Worst-case capacity = out_size*2
  // bytes (bf16 output); we need 18 MiB of scratch.
  if (ws_size < 58*MB || (long)out_size*2 < (long)18*MB){
    k_sentinel<<<1,1,0,stream>>>((u16*)d_out, 16.0f * (float)(ws_size / MB));
    return;
  }

  // ws regions (MiB offsets; params region [56,58) never aliased):
  //  conv1: FP1 [0,16) FC1 [16,32) WTCP [32,41) WTCC [41,50)      (padded x chunk lives in d_out, 17.9MB)
  //  PAM:   FB [32,34) FCc [34,36) FDTb [36,40) PV-partials [40,56)  (ATTN chunk in d_out, 16MB)
  //  CAM:   FATb [32,36) FEATC [40,56)      (Gram split-8 partials 8MB + softmax out in d_out)
  //  conv2: WT2P [16,20.5) WT2C [20.5,25)                          (padded strip in d_out, 17.9MB)
  //  heads: FUS [16,32) HP [32,35) HC [35,38) HF [38,40.6) -- HF clobbers FEATC head AFTER HC gemm
  const size_t FP1=0, FC1=16*MB, WTCP=32*MB, WTCC=41*MB,
               FB=32*MB, FCc=34*MB, FDTb=36*MB, PP=40*MB,
               FATb=32*MB, FEATC=40*MB,
               WT2P=16*MB, WT2C=WT2P+4718592,
               FUS=16*MB, HP=32*MB, HC=35*MB, HF=38*MB;
  u16* prm = P(56*MB);
  int* FLAG = (int*)(ws + 57*MB + 524288);
  u16* SCR = (u16*)d_out;   // d_out used as scratch; fully overwritten by k_upsample at the end
  const int SP1=0, BP1=512, SC1=1024, BC1=1536, SP2=2048, BP2=2560, SC2=3072, BC2=3584,
            PBB=4096, PBC=4160, PBD=4224, BP3=4736, BC3=4817, BLOG=4898, ALPHA=4979, BETA=4980,
            PWB=4992, PWC=37760, PWD=70528, W3P=332672, W3C=374144, W3L=415616;

  // ---- dtype probe + param normalization to bf16 ----
  k_probe<<<1, 256, 0, stream>>>((const unsigned*)x, FLAG);
  auto cv = [&](int di, int po, int n){
    k_cvt<<<(n+255)/256, 256, 0, stream>>>(d_in[di], prm+po, n, FLAG);
  };
  cv(2,SP1,512);  cv(3,BP1,512);  cv(5,SC1,512);  cv(6,BC1,512);
  cv(16,SP2,512); cv(17,BP2,512); cv(19,SC2,512); cv(20,BC2,512);
  cv(8,PBB,64);   cv(10,PBC,64);  cv(12,PBD,512);
  cv(24,BP3,81);  cv(26,BC3,81);  cv(22,BLOG,81);
  cv(13,ALPHA,1); cv(14,BETA,1);
  cv(7,PWB,32768); cv(9,PWC,32768); cv(11,PWD,262144);
  cv(23,W3P,41472); cv(25,W3C,41472); cv(21,W3L,41472);

  // ---- conv1 (2048->512), 2 ic-chunks of 1024, 2 batches per dispatch, P+C branch folded ----
  // 2-batch padded chunk = 17.9 MB in d_out. Branch fold: gridDim.x=8 (n-panel | branch<<2),
  // weight stride WTCC-WTCP = 4718592 elems, out stride FC1-FP1 = 8388608 elems, s/b stride 1024.
  const int BPD = 2;
  const int nbp = 4/BPD;
  k_zero<<<BPD*2178, 256, 0, stream>>>((uint4*)SCR, (long)BPD*557568);  // BPD*66*66*1024 bf16
  for (int ch=0; ch<2; ch++){
    k_wtrans<<<18432, 256, 0, stream>>>(wp1, P(WTCP), 2048, 1024, ch*1024, FLAG);
    k_wtrans<<<18432, 256, 0, stream>>>(wc1, P(WTCC), 2048, 1024, ch*1024, FLAG);
    for (int bp=0; bp<nbp; bp++){
      k_pad1<<<dim3(64,16,BPD), 256, 0, stream>>>(x, SCR, 1024, ch*1024, bp*BPD, FLAG);
      const size_t ob = (size_t)bp*BPD*4096*512;
      conv3_gemm<<<dim3(8,32*BPD), 256, 0, stream>>>(SCR, P(WTCP), 1024, P(FP1)+ob, prm+SP1, prm+BP1, ch,
                                                     4718592L, 8388608L);
    }
  }

  // ---- PAM (writes feat_p in-place over FP1) ----
  gemm_nt<<<dim3(1,128), 256, 0, stream>>>(P(FP1), prm+PWB, 64, 512, 512, 512, P(FB), 64, 1, prm+PBB, nullptr, 0, 0);
  gemm_nt<<<dim3(1,128), 256, 0, stream>>>(P(FP1), prm+PWC, 64, 512, 512, 512, P(FCc), 64, 1, prm+PBC, nullptr, 0, 0);
  for (int b=0;b<4;b++){
    const size_t fo = (size_t)b*4096*64, so = (size_t)b*4096*512;
    // FD^T directly: C[c][m] = sum_ic wd[c][ic]*feat_p[m][ic] + bd[c]  (mode 5 = row bias)
    gemm_nt<<<dim3(32,4), 256, 0, stream>>>(prm+PWD, P(FP1)+so, 4096, 512, 512, 512, P(FDTb), 4096, 5, prm+PBD, nullptr, 0, 0);
    for (int ck=0;ck<2;ck++){
      // attn chunk [2048][4096] in d_out
      gemm_nt<<<dim3(32,16), 256, 0, stream>>>(P(FB)+fo+(size_t)ck*131072, P(FCc)+fo, 4096, 64, 64, 64, SCR, 4096, 0, nullptr, nullptr, 0, 0);
      k_softmax_pam<<<2048, 256, 0, stream>>>(SCR);
      // PV split-K=4 into f32 partials, then combine with alpha + residual (in-place FP1)
      gemm_nt<<<dim3(4,16,4), 256, 0, stream>>>(SCR, P(FDTb), 512, 4096, 4096, 4096, (void*)P(PP), 512, 4, nullptr, nullptr, 1024, 4194304);
      k_pv_combine<<<1024, 256, 0, stream>>>((const float*)P(PP), P(FP1)+so+(size_t)ck*1048576, prm+ALPHA);
    }
  }

  // ---- CAM (per-batch; FEATC separate buffer; Gram matrix split-K=8, partials in d_out) ----
  u16* ATTCS = SCR + 4194304;   // after the 8MB partial region
  for (int b=0;b<4;b++){
    const size_t so = (size_t)b*4096*512;
    k_transpose<<<dim3(8,64), 256, 0, stream>>>(P(FC1)+so, P(FATb), 4096, 512);
    gemm_nt<<<dim3(4,4,8), 256, 0, stream>>>(P(FATb), P(FATb), 512, 4096, 4096, 4096, (void*)SCR, 512, 4, nullptr, nullptr, 512, 1048576);
    k_softmax_cam8<<<512, 256, 0, stream>>>((const float*)SCR, ATTCS);
    gemm_nt<<<dim3(4,32), 256, 0, stream>>>(P(FC1)+so, ATTCS, 512, 512, 512, 512, P(FEATC)+so, 512, 3, prm+BETA, P(FC1)+so, 0, 0);
  }

  // ---- conv2 pair (all-batch padded strip in d_out, in-place over FP1 / FEATC) ----
  k_wtrans<<<9216, 256, 0, stream>>>(wp2, P(WT2P), 512, 512, 0, FLAG);
  k_wtrans<<<9216, 256, 0, stream>>>(wc2, P(WT2C), 512, 512, 0, FLAG);
  k_zero<<<4356, 256, 0, stream>>>((uint4*)SCR, 1115136);  // 4*66*66*512 bf16
  k_pad_strip<<<4096, 256, 0, stream>>>(P(FP1), SCR, 512, 16384);
  conv3_gemm<<<dim3(4,128), 256, 0, stream>>>(SCR, P(WT2P), 512, P(FP1), prm+SP2, prm+BP2, 2, 0L, 0L);
  k_pad_strip<<<4096, 256, 0, stream>>>(P(FEATC), SCR, 512, 16384);
  conv3_gemm<<<dim3(4,128), 256, 0, stream>>>(SCR, P(WT2C), 512, P(FEATC), prm+SC2, prm+BC2, 2, 0L, 0L);

  // ---- heads + upsample ----
  k_add_bf16<<<4096, 256, 0, stream>>>(P(FP1), P(FEATC), P(FUS), (long)16384*512);
  gemm_nt<<<dim3(1,128), 256, 0, stream>>>(P(FP1), prm+W3P, 81, 512, 512, 512, P(HP), 81, 1, prm+BP3, nullptr, 0, 0);
  gemm_nt<<<dim3(1,128), 256, 0, stream>>>(P(FEATC), prm+W3C, 81, 512, 512, 512, P(HC), 81, 1, prm+BC3, nullptr, 0, 0);
  // HF region overlaps FEATC's first MiBs -- must run after HC gemm (stream-ordered).
  gemm_nt<<<dim3(1,128), 256, 0, stream>>>(P(FUS), prm+W3L, 81, 512, 512, 512, P(HF), 81, 1, prm+BLOG, nullptr, 0, 0);
  k_upsample<<<124416, 128, 0, stream>>>(P(HP), P(HC), P(HF), d_out, FLAG);
}

// Round 5
// 2413.859 us; speedup vs baseline: 2.5759x; 1.0249x over previous
//
#include <hip/hip_runtime.h>

typedef unsigned short u16;
typedef __bf16 bf16x8 __attribute__((ext_vector_type(8)));
typedef float f32x4 __attribute__((ext_vector_type(4)));

static __device__ __forceinline__ float bf2f(u16 v){ unsigned u=((unsigned)v)<<16; float f; __builtin_memcpy(&f,&u,4); return f; }
static __device__ __forceinline__ u16 f2bf(float f){ unsigned u; __builtin_memcpy(&u,&f,4); u += 0x7fffu + ((u>>16)&1u); return (u16)(u>>16); }

static __device__ __forceinline__ float wave_max(float v){
#pragma unroll
  for(int o=32;o;o>>=1) v=fmaxf(v,__shfl_xor(v,o,64));
  return v;
}
static __device__ __forceinline__ float wave_sum(float v){
#pragma unroll
  for(int o=32;o;o>>=1) v+=__shfl_xor(v,o,64);
  return v;
}

__global__ void k_sentinel(u16* __restrict__ o, float v){ o[0] = f2bf(v); }

// dtype probe: if any u16 half of x's first 32768 words has exponent field 0xFF,
// the data cannot be finite bf16 -> it is f32 mantissa bits. flag=1 => f32 inputs.
__global__ void k_probe(const unsigned* __restrict__ w, int* __restrict__ flag){
  __shared__ int found;
  if (threadIdx.x==0) found = 0;
  __syncthreads();
  int loc = 0;
  for (int i = threadIdx.x; i < 32768; i += 256){
    unsigned v = w[i];
    if ((((v >> 7) & 0xFFu) == 0xFFu) || (((v >> 23) & 0xFFu) == 0xFFu)) loc = 1;
  }
  if (loc) atomicOr(&found, 1);
  __syncthreads();
  if (threadIdx.x==0) *flag = found;
}

// normalize a tensor to bf16 (identity copy if already bf16)
__global__ void k_cvt(const void* __restrict__ src, u16* __restrict__ dst, int n, const int* __restrict__ flag){
  int i = blockIdx.x*256 + threadIdx.x;
  if (i >= n) return;
  if (*flag) dst[i] = f2bf(((const float*)src)[i]);
  else       dst[i] = ((const u16*)src)[i];
}

__global__ void k_zero(uint4* __restrict__ p, long n){
  long i = (long)blockIdx.x*256 + threadIdx.x;
  if (i < n) p[i] = make_uint4(0,0,0,0);
}

// NCHW x, channel window [icoff, icoff+64*gridDim.y) of batch (bbase+blockIdx.z)
// -> zero-padded NHWC [bi][66][66][ICD]
__global__ void k_pad1(const void* __restrict__ xb, u16* __restrict__ xp, int ICD, int icoff, int bbase,
                       const int* __restrict__ flag){
  __shared__ u16 tile[64][65];
  const int h = blockIdx.x;
  const int ic0 = blockIdx.y<<6;
  const int bi = blockIdx.z;
  const int t = threadIdx.x, lane = t&63, g = t>>6;
  const size_t base = ((size_t)(bbase+bi)*2048 + icoff + ic0)*4096 + (size_t)h*64;
  if (*flag){
    const float* src = (const float*)xb + base;
#pragma unroll
    for(int i=0;i<16;i++){ int icl = g*16+i; tile[icl][lane] = f2bf(src[(size_t)icl*4096 + lane]); }
  } else {
    const u16* src = (const u16*)xb + base;
#pragma unroll
    for(int i=0;i<16;i++){ int icl = g*16+i; tile[icl][lane] = src[(size_t)icl*4096 + lane]; }
  }
  __syncthreads();
  u16* dst = xp + ((size_t)bi*4356 + ((size_t)(h+1))*66 + 1)*ICD + ic0;
#pragma unroll
  for(int j=0;j<16;j++){ int w = g*16+j; dst[(size_t)w*ICD + lane] = tile[lane][w]; }
}

// OIHW 3x3 weights -> [tap][oc][icd], coalesced: each lane reads its icd's 9
// contiguous taps (wave covers a contiguous 2304B run), writes per-tap 128B chunks.
// block = 4 oc x 64 icd; grid (ICD/64, 128).
__global__ void k_wtrans2(const void* __restrict__ w, u16* __restrict__ wt, int ICS, int ICD, int icoff,
                          const int* __restrict__ flag){
  const int l = threadIdx.x & 63, g = threadIdx.x >> 6;
  const int icd = (blockIdx.x<<6) + l;
  const int oc  = (blockIdx.y<<2) + g;
  const size_t sbase = ((size_t)oc*ICS + icoff + icd)*9;
  float v[9];
  if (*flag){
    const float* s = (const float*)w + sbase;
#pragma unroll
    for(int t=0;t<9;t++) v[t] = s[t];
  } else {
    const u16* s = (const u16*)w + sbase;
#pragma unroll
    for(int t=0;t<9;t++) v[t] = bf2f(s[t]);
  }
#pragma unroll
  for(int t=0;t<9;t++) wt[((size_t)t*512 + oc)*ICD + icd] = f2bf(v[t]);
}

// bf16 transpose [R][C] -> [C][R]
__global__ void k_transpose(const u16* __restrict__ in, u16* __restrict__ outp, int R, int C){
  __shared__ u16 tile[64][65];
  const int c0 = blockIdx.x<<6, r0 = blockIdx.y<<6;
  const int t=threadIdx.x, lane=t&63, g=t>>6;
#pragma unroll
  for(int i=0;i<16;i++){ int rl=g*16+i; tile[rl][lane] = in[(size_t)(r0+rl)*C + c0 + lane]; }
  __syncthreads();
#pragma unroll
  for(int j=0;j<16;j++){ int cl=g*16+j; outp[(size_t)(c0+cl)*R + r0 + lane] = tile[lane][cl]; }
}

// NHWC strip [npix][C] -> padded [nb][66][66][C] interior (nb = npix/4096)
__global__ void k_pad_strip(const u16* __restrict__ in, u16* __restrict__ outp, int C, int npix){
  long i = (long)blockIdx.x*256 + threadIdx.x;   // vec8 index
  int vpp = C>>3;
  if (i >= (long)npix*vpp) return;
  int p = (int)(i/vpp), v = (int)(i - (long)p*vpp);
  int b = p>>12, h=(p>>6)&63, w=p&63;
  ((uint4*)outp)[((size_t)(b*66+h+1)*66 + (w+1))*vpp + v] = ((const uint4*)in)[i];
}

__global__ void k_add_bf16(const u16* __restrict__ a, const u16* __restrict__ b, u16* __restrict__ o, long n){
  long i = ((long)blockIdx.x*256 + threadIdx.x)*8;
  if (i >= n) return;
  uint4 va = *(const uint4*)(a+i), vb = *(const uint4*)(b+i);
  u16* pa=(u16*)&va; u16* pb=(u16*)&vb;
  uint4 vo; u16* po=(u16*)&vo;
#pragma unroll
  for(int e=0;e<8;e++) po[e] = f2bf(bf2f(pa[e]) + bf2f(pb[e]));
  *(uint4*)(o+i) = vo;
}

// generic NT GEMM: C[MxN] = A[MxK] * Bt[NxK]^T
// mode 0: bf16 plain; 1: bf16 + bias q1[col]; 3: bf16 alpha(q1[0])*acc + resid q2[idx];
// mode 4: f32 plain; 5: bf16 + bias q1[row].
// zk>0: split-K -- blockIdx.z selects k-window [z*zk, z*zk+zk) and offsets Cout by z*zcb bytes.
__global__ __launch_bounds__(256,2) void gemm_nt(
    const u16* __restrict__ A, const u16* __restrict__ Bt,
    int N, int K, int lda, int ldb,
    void* __restrict__ Cout, int ldc, int mode,
    const u16* __restrict__ q1, const u16* __restrict__ q2, int zk, long zcb)
{
  if (zk){
    const int zz = blockIdx.z;
    A  += (size_t)zz*zk;
    Bt += (size_t)zz*zk;
    Cout = (void*)((char*)Cout + (size_t)zz*zcb);
    K = zk;
  }
  __shared__ __align__(16) u16 As[128*40];
  __shared__ __align__(16) u16 Bs[128*40];
  const int t = threadIdx.x;
  const int m0 = blockIdx.y<<7, n0 = blockIdx.x<<7;
  const int r = t>>2, q = t&3;
  const u16* A0 = A + (size_t)(m0+r)*lda + q*8;
  const u16* A1 = A0 + (size_t)64*lda;
  const bool bv0 = (n0+r)    < N;
  const bool bv1 = (n0+r+64) < N;
  const u16* B0 = Bt + (size_t)(n0+r)*ldb + q*8;
  const u16* B1 = B0 + (size_t)64*ldb;
  const int wave=t>>6, lane=t&63;
  const int wr=(wave>>1)<<6, wc=(wave&1)<<6, fm=lane&15, kg=lane>>4;
  f32x4 acc[4][4] = {};
  for (int k0=0; k0<K; k0+=32){
    uint4 a0 = *(const uint4*)(A0+k0);
    uint4 a1 = *(const uint4*)(A1+k0);
    uint4 b0 = bv0 ? *(const uint4*)(B0+k0) : make_uint4(0,0,0,0);
    uint4 b1 = bv1 ? *(const uint4*)(B1+k0) : make_uint4(0,0,0,0);
    __syncthreads();
    *(uint4*)&As[r*40+q*8] = a0;
    *(uint4*)&As[(r+64)*40+q*8] = a1;
    *(uint4*)&Bs[r*40+q*8] = b0;
    *(uint4*)&Bs[(r+64)*40+q*8] = b1;
    __syncthreads();
    bf16x8 af[4], bfr[4];
#pragma unroll
    for(int i=0;i<4;i++) af[i]  = *(const bf16x8*)&As[(wr+i*16+fm)*40 + kg*8];
#pragma unroll
    for(int j=0;j<4;j++) bfr[j] = *(const bf16x8*)&Bs[(wc+j*16+fm)*40 + kg*8];
#pragma unroll
    for(int i=0;i<4;i++)
#pragma unroll
      for(int j=0;j<4;j++)
        acc[i][j] = __builtin_amdgcn_mfma_f32_16x16x32_bf16(af[i], bfr[j], acc[i][j], 0,0,0);
  }
  const float alpha = (mode==3) ? bf2f(q1[0]) : 0.f;
#pragma unroll
  for(int j=0;j<4;j++){
    int col = n0 + wc + j*16 + fm;
    if (col >= N) continue;
    float bias = (mode==1) ? bf2f(q1[col]) : 0.f;
#pragma unroll
    for(int i=0;i<4;i++){
      int row = m0 + wr + i*16 + (kg<<2);
#pragma unroll
      for(int rr=0;rr<4;rr++){
        long idx = (long)(row+rr)*ldc + col;
        float v = acc[i][j][rr];
        if (mode==4)      ((float*)Cout)[idx] = v;
        else if (mode==3) ((u16*)Cout)[idx] = f2bf(alpha*v + bf2f(q2[idx]));
        else if (mode==5) ((u16*)Cout)[idx] = f2bf(v + bf2f(q1[row+rr]));
        else if (mode==1) ((u16*)Cout)[idx] = f2bf(v + bias);
        else              ((u16*)Cout)[idx] = f2bf(v);
      }
    }
  }
}

// implicit-GEMM 3x3 conv (padded NHWC in, tap-major weights, OC=512)
// IC-outer / tap-inner loop: the 9 taps' A-loads per 32-IC chunk hit a ~16KB window
// (L1/L2-resident) instead of re-streaming X per tap.
// XCD swizzle: lid%8 = XCD gets an m-band (gridDim.y/8 tiles) x all (panel,branch)
// combos, so blocks sharing an A-window co-reside on one XCD; weight slabs stream once.
// gridDim.x*gridDim.y blocks; nbr = panel | branch<<2 (branch strides weight/out/s/b).
// phase 0: Out = raw partial (bf16);  1: Out = relu(s*(Out + acc) + b);  2: Out = relu(s*acc + b)
__global__ __launch_bounds__(256,2) void conv3_gemm(
    const u16* __restrict__ Xp, const u16* __restrict__ Wt, int ICt,
    u16* __restrict__ Out, const u16* __restrict__ scale, const u16* __restrict__ bias, int phase,
    long wstr, long ostr)
{
  __shared__ __align__(16) u16 As[128*40];
  __shared__ __align__(16) u16 Bs[128*40];
  const int t = threadIdx.x;
  const int per8 = gridDim.y >> 3;                      // m-tiles per XCD band (pow2: 8 or 16)
  const int lid = blockIdx.x + blockIdx.y*gridDim.x;
  const int k8 = lid & 7, jj = lid >> 3;
  const int mt = k8*per8 + (jj & (per8-1));
  const int nbr = jj / per8;
  const int brn = nbr>>2;
  const int m0 = mt<<7, n0 = (nbr&3)<<7;
  const u16* Wb = Wt + (size_t)brn*wstr;
  u16* Ob = Out + (size_t)brn*ostr;
  const u16* scb = scale + brn*1024;
  const u16* bib = bias + brn*1024;
  const int r = t>>2, q = t&3;
  const int p0 = m0 + r, p1 = p0 + 64;
  const size_t xb0 = ((size_t)((p0>>12)*66 + ((p0>>6)&63))*66 + (p0&63))*ICt + q*8;
  const size_t xb1 = ((size_t)((p1>>12)*66 + ((p1>>6)&63))*66 + (p1&63))*ICt + q*8;
  const u16* W0 = Wb + (size_t)(n0+r)*ICt + q*8;
  const u16* W1 = W0 + (size_t)64*ICt;
  const size_t wtap = (size_t)512*ICt;
  const int wave=t>>6, lane=t&63;
  const int wr=(wave>>1)<<6, wc=(wave&1)<<6, fm=lane&15, kg=lane>>4;
  f32x4 acc[4][4] = {};
  for (int k0=0; k0<ICt; k0+=32){
    for (int tap=0; tap<9; tap++){
      const size_t toff = (size_t)((tap/3)*66 + (tap%3))*ICt + k0;
      const u16* xa0 = Xp + xb0 + toff;
      const u16* xa1 = Xp + xb1 + toff;
      const u16* wa0 = W0 + (size_t)tap*wtap + k0;
      const u16* wa1 = W1 + (size_t)tap*wtap + k0;
      uint4 a0 = *(const uint4*)(xa0);
      uint4 a1 = *(const uint4*)(xa1);
      uint4 b0 = *(const uint4*)(wa0);
      uint4 b1 = *(const uint4*)(wa1);
      __syncthreads();
      *(uint4*)&As[r*40+q*8] = a0;
      *(uint4*)&As[(r+64)*40+q*8] = a1;
      *(uint4*)&Bs[r*40+q*8] = b0;
      *(uint4*)&Bs[(r+64)*40+q*8] = b1;
      __syncthreads();
      bf16x8 af[4], bfr[4];
#pragma unroll
      for(int i=0;i<4;i++) af[i]  = *(const bf16x8*)&As[(wr+i*16+fm)*40 + kg*8];
#pragma unroll
      for(int j=0;j<4;j++) bfr[j] = *(const bf16x8*)&Bs[(wc+j*16+fm)*40 + kg*8];
#pragma unroll
      for(int i=0;i<4;i++)
#pragma unroll
        for(int j=0;j<4;j++)
          acc[i][j] = __builtin_amdgcn_mfma_f32_16x16x32_bf16(af[i], bfr[j], acc[i][j], 0,0,0);
    }
  }
#pragma unroll
  for(int j=0;j<4;j++){
    int col = n0 + wc + j*16 + fm;
    float s = bf2f(scb[col]), bb = bf2f(bib[col]);
#pragma unroll
    for(int i=0;i<4;i++){
      int row = m0 + wr + i*16 + (kg<<2);
#pragma unroll
      for(int rr=0;rr<4;rr++){
        size_t idx = (size_t)(row+rr)*512 + col;
        float v = acc[i][j][rr];
        if (phase == 0)      Ob[idx] = f2bf(v);
        else if (phase == 1) Ob[idx] = f2bf(fmaxf(s*(bf2f(Ob[idx]) + v) + bb, 0.f));
        else                 Ob[idx] = f2bf(fmaxf(s*v + bb, 0.f));
      }
    }
  }
}

// PAM row softmax, in-place over rows of 4096 bf16
__global__ __launch_bounds__(256) void k_softmax_pam(u16* __restrict__ attn){
  __shared__ float red[8];
  u16* row = attn + (size_t)blockIdx.x*4096;
  uint4* rv = (uint4*)row;
  const int t = threadIdx.x;
  uint4 c0 = rv[2*t], c1 = rv[2*t+1];
  u16* e0 = (u16*)&c0; u16* e1=(u16*)&c1;
  float v[16];
#pragma unroll
  for(int i=0;i<8;i++){ v[i]=bf2f(e0[i]); v[8+i]=bf2f(e1[i]); }
  float mx = v[0];
#pragma unroll
  for(int i=1;i<16;i++) mx = fmaxf(mx, v[i]);
  mx = wave_max(mx);
  if((t&63)==0) red[t>>6] = mx;
  __syncthreads();
  mx = fmaxf(fmaxf(red[0],red[1]),fmaxf(red[2],red[3]));
  float s = 0.f;
#pragma unroll
  for(int i=0;i<16;i++){ v[i]=__expf(v[i]-mx); s += v[i]; }
  s = wave_sum(s);
  if((t&63)==0) red[4+(t>>6)] = s;
  __syncthreads();
  s = red[4]+red[5]+red[6]+red[7];
  float inv = 1.f/s;
#pragma unroll
  for(int i=0;i<8;i++){ e0[i]=f2bf(v[i]*inv); e1[i]=f2bf(v[8+i]*inv); }
  rv[2*t]=c0; rv[2*t+1]=c1;
}

// PV split-K combine: io = f2bf(alpha * (P0+P1+P2+P3) + io)   (4 splits of 2048x512 f32)
__global__ __launch_bounds__(256) void k_pv_combine(const float* __restrict__ Pp, u16* __restrict__ io,
                                                    const u16* __restrict__ alpha){
  const int i = blockIdx.x*256 + threadIdx.x;     // float4 index, 262144 total
  const float4* p = (const float4*)Pp;
  float4 a0 = p[i], a1 = p[i+262144], a2 = p[i+524288], a3 = p[i+786432];
  const float al = bf2f(alpha[0]);
  ushort4 d = ((const ushort4*)io)[i];
  ushort4 o;
  o.x = f2bf(al*(a0.x+a1.x+a2.x+a3.x) + bf2f(d.x));
  o.y = f2bf(al*(a0.y+a1.y+a2.y+a3.y) + bf2f(d.y));
  o.z = f2bf(al*(a0.z+a1.z+a2.z+a3.z) + bf2f(d.z));
  o.w = f2bf(al*(a0.w+a1.w+a2.w+a3.w) + bf2f(d.w));
  ((ushort4*)io)[i] = o;
}

// CAM softmax over split-K partial sums: out[c][d] = softmax_d(-(sum of 8 partials))
__global__ __launch_bounds__(256) void k_softmax_cam8(const float* __restrict__ P8, u16* __restrict__ outp){
  __shared__ float red[8];
  const int t = threadIdx.x;
  const float* r0 = P8 + (size_t)blockIdx.x*512;  // split stride 262144 floats (512x512)
  float a = 0.f, b2 = 0.f;
#pragma unroll
  for(int s2=0;s2<8;s2++){ a += r0[(size_t)s2*262144 + t]; b2 += r0[(size_t)s2*262144 + 256 + t]; }
  a = -a; b2 = -b2;
  float mx = wave_max(fmaxf(a,b2));
  if((t&63)==0) red[t>>6]=mx;
  __syncthreads();
  mx = fmaxf(fmaxf(red[0],red[1]),fmaxf(red[2],red[3]));
  float ea = __expf(a-mx), eb = __expf(b2-mx);
  float s = wave_sum(ea+eb);
  if((t&63)==0) red[4+(t>>6)]=s;
  __syncthreads();
  s = red[4]+red[5]+red[6]+red[7];
  float inv = 1.f/s;
  u16* orow = outp + (size_t)blockIdx.x*512;
  orow[t] = f2bf(ea*inv); orow[t+256] = f2bf(eb*inv);
}

// bilinear 2x upsample (half-pixel, clamp), NHWC[16384][81] -> NCHW out (f32 or bf16 per flag)
__global__ __launch_bounds__(128) void k_upsample(const u16* __restrict__ hp, const u16* __restrict__ hc,
                                                  const u16* __restrict__ hf, void* __restrict__ outp,
                                                  const int* __restrict__ flag){
  int bx = blockIdx.x;
  const int y = bx & 127; bx >>= 7;
  const int ch = bx % 81; bx /= 81;
  const int b = bx & 3; const int head = bx >> 2;
  const u16* src = (head==0) ? hp : (head==1 ? hc : hf);
  const int xo = threadIdx.x;
  float fy = y*0.5f - 0.25f, fx = xo*0.5f - 0.25f;
  float fy0 = floorf(fy), fx0 = floorf(fx);
  float wy = fy - fy0, wx = fx - fx0;
  int y0 = max((int)fy0, 0), y1 = min((int)fy0 + 1, 63);
  int x0 = max((int)fx0, 0), x1 = min((int)fx0 + 1, 63);
  const size_t bb = (size_t)b*4096;
  float v00 = bf2f(src[(bb + y0*64 + x0)*81 + ch]);
  float v01 = bf2f(src[(bb + y0*64 + x1)*81 + ch]);
  float v10 = bf2f(src[(bb + y1*64 + x0)*81 + ch]);
  float v11 = bf2f(src[(bb + y1*64 + x1)*81 + ch]);
  float v = (1.f-wy)*((1.f-wx)*v00 + wx*v01) + wy*((1.f-wx)*v10 + wx*v11);
  size_t oidx = ((size_t)(head*324 + b*81 + ch))*16384 + (size_t)y*128 + xo;
  if (*flag) ((float*)outp)[oidx] = v;
  else       ((u16*)outp)[oidx]  = f2bf(v);
}

extern "C" void kernel_launch(void* const* d_in, const int* in_sizes, int n_in,
                              void* d_out, int out_size, void* d_ws, size_t ws_size,
                              hipStream_t stream)
{
  (void)in_sizes; (void)n_in;
  const void* x   = d_in[0];
  const void* wp1 = d_in[1];
  const void* wc1 = d_in[4];
  const void* wp2 = d_in[15];
  const void* wc2 = d_in[18];
  char* ws = (char*)d_ws;
  const size_t MB = 1048576;
  auto P = [&](size_t off){ return (u16*)(ws + off); };

  // ws probe: plan needs 58 MiB of workspace.
  // d_out is used as scratch; out_size is an ELEMENT count. Worst-case capacity = out_size*2
  // bytes (bf16 output); we need 18 MiB of scratch.
  if (ws_size < 58*MB || (long)out_size*2 < (long)18*MB){
    k_sentinel<<<1,1,0,stream>>>((u16*)d_out, 16.0f * (float)(ws_size / MB));
    return;
  }

  // ws regions (MiB offsets; params region [56,58) never aliased):
  //  conv1: FP1 [0,16) FC1 [16,32) WTCP [32,41) WTCC [41,50)      (padded x chunk lives in d_out, 17.9MB)
  //  PAM:   FB [32,36) (fb|fc merged, ld=128) FDTb [36,40) PV-partials [40,56)  (ATTN chunk in d_out, 16MB)
  //  CAM:   FATb [32,36) FEATC [40,56)      (Gram split-8 partials 8MB + softmax out in d_out)
  //  conv2: WT2P [16,20.5) WT2C [20.5,25)                          (padded strip in d_out, 17.9MB)
  //  heads: FUS [16,32) HP [32,35) HC [35,38) HF [38,40.6) -- HF clobbers FEATC head AFTER HC gemm
  const size_t FP1=0, FC1=16*MB, WTCP=32*MB, WTCC=41*MB,
               FB=32*MB, FDTb=36*MB, PP=40*MB,
               FATb=32*MB, FEATC=40*MB,
               WT2P=16*MB, WT2C=WT2P+4718592,
               FUS=16*MB, HP=32*MB, HC=35*MB, HF=38*MB;
  u16* prm = P(56*MB);
  int* FLAG = (int*)(ws + 57*MB + 524288);
  u16* SCR = (u16*)d_out;   // d_out used as scratch; fully overwritten by k_upsample at the end
  const int SP1=0, BP1=512, SC1=1024, BC1=1536, SP2=2048, BP2=2560, SC2=3072, BC2=3584,
            PBB=4096, PBC=4160, PBD=4224, BP3=4736, BC3=4817, BLOG=4898, ALPHA=4979, BETA=4980,
            PWB=4992, PWC=37760, PWD=70528, W3P=332672, W3C=374144, W3L=415616;

  // ---- dtype probe + param normalization to bf16 ----
  k_probe<<<1, 256, 0, stream>>>((const unsigned*)x, FLAG);
  auto cv = [&](int di, int po, int n){
    k_cvt<<<(n+255)/256, 256, 0, stream>>>(d_in[di], prm+po, n, FLAG);
  };
  cv(2,SP1,512);  cv(3,BP1,512);  cv(5,SC1,512);  cv(6,BC1,512);
  cv(16,SP2,512); cv(17,BP2,512); cv(19,SC2,512); cv(20,BC2,512);
  cv(8,PBB,64);   cv(10,PBC,64);  cv(12,PBD,512);
  cv(24,BP3,81);  cv(26,BC3,81);  cv(22,BLOG,81);
  cv(13,ALPHA,1); cv(14,BETA,1);
  cv(7,PWB,32768); cv(9,PWC,32768); cv(11,PWD,262144);
  cv(23,W3P,41472); cv(25,W3C,41472); cv(21,W3L,41472);

  // ---- conv1 (2048->512), 2 ic-chunks of 1024, 2 batches per dispatch, P+C branch folded ----
  // 2-batch padded chunk = 17.9 MB in d_out. gridDim.y=64 (8 m-tiles/XCD band).
  const int BPD = 2;
  const int nbp = 4/BPD;
  k_zero<<<BPD*2178, 256, 0, stream>>>((uint4*)SCR, (long)BPD*557568);  // BPD*66*66*1024 bf16
  for (int ch=0; ch<2; ch++){
    k_wtrans2<<<dim3(16,128), 256, 0, stream>>>(wp1, P(WTCP), 2048, 1024, ch*1024, FLAG);
    k_wtrans2<<<dim3(16,128), 256, 0, stream>>>(wc1, P(WTCC), 2048, 1024, ch*1024, FLAG);
    for (int bp=0; bp<nbp; bp++){
      k_pad1<<<dim3(64,16,BPD), 256, 0, stream>>>(x, SCR, 1024, ch*1024, bp*BPD, FLAG);
      const size_t ob = (size_t)bp*BPD*4096*512;
      conv3_gemm<<<dim3(8,32*BPD), 256, 0, stream>>>(SCR, P(WTCP), 1024, P(FP1)+ob, prm+SP1, prm+BP1, ch,
                                                     4718592L, 8388608L);
    }
  }

  // ---- PAM (writes feat_p in-place over FP1) ----
  // FB/FCc merged: PWB|PWC adjacent (N=128), PBB|PBC adjacent; out [16384][128] (fb=cols 0-63, fc=64-127)
  gemm_nt<<<dim3(1,128), 256, 0, stream>>>(P(FP1), prm+PWB, 128, 512, 512, 512, P(FB), 128, 1, prm+PBB, nullptr, 0, 0);
  for (int b=0;b<4;b++){
    const size_t fo = (size_t)b*4096*128, so = (size_t)b*4096*512;
    // FD^T directly: C[c][m] = sum_ic wd[c][ic]*feat_p[m][ic] + bd[c]  (mode 5 = row bias)
    gemm_nt<<<dim3(32,4), 256, 0, stream>>>(prm+PWD, P(FP1)+so, 4096, 512, 512, 512, P(FDTb), 4096, 5, prm+PBD, nullptr, 0, 0);
    for (int ck=0;ck<2;ck++){
      // attn chunk [2048][4096] in d_out (A = fb rows, B = fc rows; both ld=128)
      gemm_nt<<<dim3(32,16), 256, 0, stream>>>(P(FB)+fo+(size_t)ck*262144, P(FB)+64+fo, 4096, 64, 128, 128, SCR, 4096, 0, nullptr, nullptr, 0, 0);
      k_softmax_pam<<<2048, 256, 0, stream>>>(SCR);
      // PV split-K=4 into f32 partials, then combine with alpha + residual (in-place FP1)
      gemm_nt<<<dim3(4,16,4), 256, 0, stream>>>(SCR, P(FDTb), 512, 4096, 4096, 4096, (void*)P(PP), 512, 4, nullptr, nullptr, 1024, 4194304);
      k_pv_combine<<<1024, 256, 0, stream>>>((const float*)P(PP), P(FP1)+so+(size_t)ck*1048576, prm+ALPHA);
    }
  }

  // ---- CAM (per-batch; FEATC separate buffer; Gram matrix split-K=8, partials in d_out) ----
  u16* ATTCS = SCR + 4194304;   // after the 8MB partial region
  for (int b=0;b<4;b++){
    const size_t so = (size_t)b*4096*512;
    k_transpose<<<dim3(8,64), 256, 0, stream>>>(P(FC1)+so, P(FATb), 4096, 512);
    gemm_nt<<<dim3(4,4,8), 256, 0, stream>>>(P(FATb), P(FATb), 512, 4096, 4096, 4096, (void*)SCR, 512, 4, nullptr, nullptr, 512, 1048576);
    k_softmax_cam8<<<512, 256, 0, stream>>>((const float*)SCR, ATTCS);
    gemm_nt<<<dim3(4,32), 256, 0, stream>>>(P(FC1)+so, ATTCS, 512, 512, 512, 512, P(FEATC)+so, 512, 3, prm+BETA, P(FC1)+so, 0, 0);
  }

  // ---- conv2 pair (all-batch padded strip in d_out, in-place over FP1 / FEATC) ----
  k_wtrans2<<<dim3(8,128), 256, 0, stream>>>(wp2, P(WT2P), 512, 512, 0, FLAG);
  k_wtrans2<<<dim3(8,128), 256, 0, stream>>>(wc2, P(WT2C), 512, 512, 0, FLAG);
  k_zero<<<4356, 256, 0, stream>>>((uint4*)SCR, 1115136);  // 4*66*66*512 bf16
  k_pad_strip<<<4096, 256, 0, stream>>>(P(FP1), SCR, 512, 16384);
  conv3_gemm<<<dim3(4,128), 256, 0, stream>>>(SCR, P(WT2P), 512, P(FP1), prm+SP2, prm+BP2, 2, 0L, 0L);
  k_pad_strip<<<4096, 256, 0, stream>>>(P(FEATC), SCR, 512, 16384);
  conv3_gemm<<<dim3(4,128), 256, 0, stream>>>(SCR, P(WT2C), 512, P(FEATC), prm+SC2, prm+BC2, 2, 0L, 0L);

  // ---- heads + upsample ----
  k_add_bf16<<<4096, 256, 0, stream>>>(P(FP1), P(FEATC), P(FUS), (long)16384*512);
  gemm_nt<<<dim3(1,128), 256, 0, stream>>>(P(FP1), prm+W3P, 81, 512, 512, 512, P(HP), 81, 1, prm+BP3, nullptr, 0, 0);
  gemm_nt<<<dim3(1,128), 256, 0, stream>>>(P(FEATC), prm+W3C, 81, 512, 512, 512, P(HC), 81, 1, prm+BC3, nullptr, 0, 0);
  // HF region overlaps FEATC's first MiBs -- must run after HC gemm (stream-ordered).
  gemm_nt<<<dim3(1,128), 256, 0, stream>>>(P(FUS), prm+W3L, 81, 512, 512, 512, P(HF), 81, 1, prm+BLOG, nullptr, 0, 0);
  k_upsample<<<124416, 128, 0, stream>>>(P(HP), P(HC), P(HF), d_out, FLAG);
}

// Round 7
// 2334.533 us; speedup vs baseline: 2.6634x; 1.0340x over previous
//
#include <hip/hip_runtime.h>

typedef unsigned short u16;
typedef __bf16 bf16x8 __attribute__((ext_vector_type(8)));
typedef float f32x4 __attribute__((ext_vector_type(4)));

static __device__ __forceinline__ float bf2f(u16 v){ unsigned u=((unsigned)v)<<16; float f; __builtin_memcpy(&f,&u,4); return f; }
static __device__ __forceinline__ u16 f2bf(float f){ unsigned u; __builtin_memcpy(&u,&f,4); u += 0x7fffu + ((u>>16)&1u); return (u16)(u>>16); }

// async global->LDS DMA, 16B per lane; LDS dest = wave-uniform base + lane*16
static __device__ __forceinline__ void gld16(const u16* g, u16* l){
  __builtin_amdgcn_global_load_lds((const __attribute__((address_space(1))) void*)g,
                                   (__attribute__((address_space(3))) void*)l, 16, 0, 0);
}

static __device__ __forceinline__ float wave_max(float v){
#pragma unroll
  for(int o=32;o;o>>=1) v=fmaxf(v,__shfl_xor(v,o,64));
  return v;
}
static __device__ __forceinline__ float wave_sum(float v){
#pragma unroll
  for(int o=32;o;o>>=1) v+=__shfl_xor(v,o,64);
  return v;
}

__global__ void k_sentinel(u16* __restrict__ o, float v){ o[0] = f2bf(v); }

// dtype probe: if any u16 half of x's first 32768 words has exponent field 0xFF,
// the data cannot be finite bf16 -> it is f32 mantissa bits. flag=1 => f32 inputs.
__global__ void k_probe(const unsigned* __restrict__ w, int* __restrict__ flag){
  __shared__ int found;
  if (threadIdx.x==0) found = 0;
  __syncthreads();
  int loc = 0;
  for (int i = threadIdx.x; i < 32768; i += 256){
    unsigned v = w[i];
    if ((((v >> 7) & 0xFFu) == 0xFFu) || (((v >> 23) & 0xFFu) == 0xFFu)) loc = 1;
  }
  if (loc) atomicOr(&found, 1);
  __syncthreads();
  if (threadIdx.x==0) *flag = found;
}

// normalize a tensor to bf16 (identity copy if already bf16)
__global__ void k_cvt(const void* __restrict__ src, u16* __restrict__ dst, int n, const int* __restrict__ flag){
  int i = blockIdx.x*256 + threadIdx.x;
  if (i >= n) return;
  if (*flag) dst[i] = f2bf(((const float*)src)[i]);
  else       dst[i] = ((const u16*)src)[i];
}

__global__ void k_zero(uint4* __restrict__ p, long n){
  long i = (long)blockIdx.x*256 + threadIdx.x;
  if (i < n) p[i] = make_uint4(0,0,0,0);
}

// NCHW x, channel window [icoff, icoff+64*gridDim.y) of batch (bbase+blockIdx.z)
// -> zero-padded NHWC [bi][66][66][ICD]
__global__ void k_pad1(const void* __restrict__ xb, u16* __restrict__ xp, int ICD, int icoff, int bbase,
                       const int* __restrict__ flag){
  __shared__ u16 tile[64][65];
  const int h = blockIdx.x;
  const int ic0 = blockIdx.y<<6;
  const int bi = blockIdx.z;
  const int t = threadIdx.x, lane = t&63, g = t>>6;
  const size_t base = ((size_t)(bbase+bi)*2048 + icoff + ic0)*4096 + (size_t)h*64;
  if (*flag){
    const float* src = (const float*)xb + base;
#pragma unroll
    for(int i=0;i<16;i++){ int icl = g*16+i; tile[icl][lane] = f2bf(src[(size_t)icl*4096 + lane]); }
  } else {
    const u16* src = (const u16*)xb + base;
#pragma unroll
    for(int i=0;i<16;i++){ int icl = g*16+i; tile[icl][lane] = src[(size_t)icl*4096 + lane]; }
  }
  __syncthreads();
  u16* dst = xp + ((size_t)bi*4356 + ((size_t)(h+1))*66 + 1)*ICD + ic0;
#pragma unroll
  for(int j=0;j<16;j++){ int w = g*16+j; dst[(size_t)w*ICD + lane] = tile[lane][w]; }
}

// OIHW 3x3 weights -> [tap][oc][icd], coalesced: each lane reads its icd's 9
// contiguous taps, writes per-tap 128B chunks. block = 4 oc x 64 icd; grid (ICD/64, 128).
__global__ void k_wtrans2(const void* __restrict__ w, u16* __restrict__ wt, int ICS, int ICD, int icoff,
                          const int* __restrict__ flag){
  const int l = threadIdx.x & 63, g = threadIdx.x >> 6;
  const int icd = (blockIdx.x<<6) + l;
  const int oc  = (blockIdx.y<<2) + g;
  const size_t sbase = ((size_t)oc*ICS + icoff + icd)*9;
  float v[9];
  if (*flag){
    const float* s = (const float*)w + sbase;
#pragma unroll
    for(int t=0;t<9;t++) v[t] = s[t];
  } else {
    const u16* s = (const u16*)w + sbase;
#pragma unroll
    for(int t=0;t<9;t++) v[t] = bf2f(s[t]);
  }
#pragma unroll
  for(int t=0;t<9;t++) wt[((size_t)t*512 + oc)*ICD + icd] = f2bf(v[t]);
}

// bf16 transpose [R][C] -> [C][R]
__global__ void k_transpose(const u16* __restrict__ in, u16* __restrict__ outp, int R, int C){
  __shared__ u16 tile[64][65];
  const int c0 = blockIdx.x<<6, r0 = blockIdx.y<<6;
  const int t=threadIdx.x, lane=t&63, g=t>>6;
#pragma unroll
  for(int i=0;i<16;i++){ int rl=g*16+i; tile[rl][lane] = in[(size_t)(r0+rl)*C + c0 + lane]; }
  __syncthreads();
#pragma unroll
  for(int j=0;j<16;j++){ int cl=g*16+j; outp[(size_t)(c0+cl)*R + r0 + lane] = tile[lane][cl]; }
}

// NHWC strip [npix][C] -> padded [nb][66][66][C] interior (nb = npix/4096)
__global__ void k_pad_strip(const u16* __restrict__ in, u16* __restrict__ outp, int C, int npix){
  long i = (long)blockIdx.x*256 + threadIdx.x;   // vec8 index
  int vpp = C>>3;
  if (i >= (long)npix*vpp) return;
  int p = (int)(i/vpp), v = (int)(i - (long)p*vpp);
  int b = p>>12, h=(p>>6)&63, w=p&63;
  ((uint4*)outp)[((size_t)(b*66+h+1)*66 + (w+1))*vpp + v] = ((const uint4*)in)[i];
}

__global__ void k_add_bf16(const u16* __restrict__ a, const u16* __restrict__ b, u16* __restrict__ o, long n){
  long i = ((long)blockIdx.x*256 + threadIdx.x)*8;
  if (i >= n) return;
  uint4 va = *(const uint4*)(a+i), vb = *(const uint4*)(b+i);
  u16* pa=(u16*)&va; u16* pb=(u16*)&vb;
  uint4 vo; u16* po=(u16*)&vo;
#pragma unroll
  for(int e=0;e<8;e++) po[e] = f2bf(bf2f(pa[e]) + bf2f(pb[e]));
  *(uint4*)(o+i) = vo;
}

// generic NT GEMM: C[MxN] = A[MxK] * Bt[NxK]^T
// mode 0: bf16 plain; 1: bf16 + bias q1[col]; 3: bf16 alpha(q1[0])*acc + resid q2[idx];
// mode 4: f32 plain; 5: bf16 + bias q1[row].
// zk>0: split-K -- blockIdx.z selects k-window [z*zk, z*zk+zk) and offsets Cout by z*zcb bytes.
__global__ __launch_bounds__(256,2) void gemm_nt(
    const u16* __restrict__ A, const u16* __restrict__ Bt,
    int N, int K, int lda, int ldb,
    void* __restrict__ Cout, int ldc, int mode,
    const u16* __restrict__ q1, const u16* __restrict__ q2, int zk, long zcb)
{
  if (zk){
    const int zz = blockIdx.z;
    A  += (size_t)zz*zk;
    Bt += (size_t)zz*zk;
    Cout = (void*)((char*)Cout + (size_t)zz*zcb);
    K = zk;
  }
  __shared__ __align__(16) u16 As[128*40];
  __shared__ __align__(16) u16 Bs[128*40];
  const int t = threadIdx.x;
  const int m0 = blockIdx.y<<7, n0 = blockIdx.x<<7;
  const int r = t>>2, q = t&3;
  const u16* A0 = A + (size_t)(m0+r)*lda + q*8;
  const u16* A1 = A0 + (size_t)64*lda;
  const bool bv0 = (n0+r)    < N;
  const bool bv1 = (n0+r+64) < N;
  const u16* B0 = Bt + (size_t)(n0+r)*ldb + q*8;
  const u16* B1 = B0 + (size_t)64*ldb;
  const int wave=t>>6, lane=t&63;
  const int wr=(wave>>1)<<6, wc=(wave&1)<<6, fm=lane&15, kg=lane>>4;
  f32x4 acc[4][4] = {};
  for (int k0=0; k0<K; k0+=32){
    uint4 a0 = *(const uint4*)(A0+k0);
    uint4 a1 = *(const uint4*)(A1+k0);
    uint4 b0 = bv0 ? *(const uint4*)(B0+k0) : make_uint4(0,0,0,0);
    uint4 b1 = bv1 ? *(const uint4*)(B1+k0) : make_uint4(0,0,0,0);
    __syncthreads();
    *(uint4*)&As[r*40+q*8] = a0;
    *(uint4*)&As[(r+64)*40+q*8] = a1;
    *(uint4*)&Bs[r*40+q*8] = b0;
    *(uint4*)&Bs[(r+64)*40+q*8] = b1;
    __syncthreads();
    bf16x8 af[4], bfr[4];
#pragma unroll
    for(int i=0;i<4;i++) af[i]  = *(const bf16x8*)&As[(wr+i*16+fm)*40 + kg*8];
#pragma unroll
    for(int j=0;j<4;j++) bfr[j] = *(const bf16x8*)&Bs[(wc+j*16+fm)*40 + kg*8];
#pragma unroll
    for(int i=0;i<4;i++)
#pragma unroll
      for(int j=0;j<4;j++)
        acc[i][j] = __builtin_amdgcn_mfma_f32_16x16x32_bf16(af[i], bfr[j], acc[i][j], 0,0,0);
  }
  const float alpha = (mode==3) ? bf2f(q1[0]) : 0.f;
#pragma unroll
  for(int j=0;j<4;j++){
    int col = n0 + wc + j*16 + fm;
    if (col >= N) continue;
    float bias = (mode==1) ? bf2f(q1[col]) : 0.f;
#pragma unroll
    for(int i=0;i<4;i++){
      int row = m0 + wr + i*16 + (kg<<2);
#pragma unroll
      for(int rr=0;rr<4;rr++){
        long idx = (long)(row+rr)*ldc + col;
        float v = acc[i][j][rr];
        if (mode==4)      ((float*)Cout)[idx] = v;
        else if (mode==3) ((u16*)Cout)[idx] = f2bf(alpha*v + bf2f(q2[idx]));
        else if (mode==5) ((u16*)Cout)[idx] = f2bf(v + bf2f(q1[row+rr]));
        else if (mode==1) ((u16*)Cout)[idx] = f2bf(v + bias);
        else              ((u16*)Cout)[idx] = f2bf(v);
      }
    }
  }
}

// implicit-GEMM 3x3 conv (padded NHWC in, tap-major weights, OC=512).
// Staging via global_load_lds DMA (no VGPR round-trip): unpadded LDS [128][32]
// so the HW's (wave-uniform base + lane*16B) placement maps to (row = lane>>2,
// kcol = lane&3). ds_reads cover a dense 1KB window per wave -> conflict-free.
// IC-outer / tap-inner for L2 tap-reuse; XCD swizzle (lid%8 = XCD gets an m-band).
// phase 0: raw bf16; 1: relu(s*(Out+acc)+b); 2: relu(s*acc+b)
__global__ __launch_bounds__(256,2) void conv3_gemm(
    const u16* __restrict__ Xp, const u16* __restrict__ Wt, int ICt,
    u16* __restrict__ Out, const u16* __restrict__ scale, const u16* __restrict__ bias, int phase,
    long wstr, long ostr)
{
  __shared__ __align__(16) u16 As[128*32];
  __shared__ __align__(16) u16 Bs[128*32];
  const int t = threadIdx.x;
  const int per8 = gridDim.y >> 3;
  const int lid = blockIdx.x + blockIdx.y*gridDim.x;
  const int k8 = lid & 7, jj = lid >> 3;
  const int mt = k8*per8 + (jj & (per8-1));
  const int nbr = jj / per8;
  const int brn = nbr>>2;
  const int m0 = mt<<7, n0 = (nbr&3)<<7;
  const u16* Wb = Wt + (size_t)brn*wstr;
  u16* Ob = Out + (size_t)brn*ostr;
  const u16* scb = scale + brn*1024;
  const u16* bib = bias + brn*1024;
  const int wave=t>>6, lane=t&63;
  // staging: wave w fills rows [w*32, w*32+32) of As and Bs via two 16-row DMAs each
  const int rsub = lane>>2;           // row within a 16-row DMA
  const int ksub = (lane&3)*8;        // 16B column chunk within the 32-elem row
  const u16* xg[2]; const u16* wg[2];
#pragma unroll
  for (int i=0;i<2;i++){
    int ra = wave*32 + i*16 + rsub;
    int p = m0 + ra;
    xg[i] = Xp + ((size_t)((p>>12)*66 + ((p>>6)&63))*66 + (p&63))*ICt + ksub;
    wg[i] = Wb + (size_t)(n0 + ra)*ICt + ksub;
  }
  u16* lA0 = As + (wave*32)*32;       // wave-uniform LDS bases
  u16* lA1 = As + (wave*32+16)*32;
  u16* lB0 = Bs + (wave*32)*32;
  u16* lB1 = Bs + (wave*32+16)*32;
  const size_t wtap = (size_t)512*ICt;
  const int wr=(wave>>1)<<6, wc=(wave&1)<<6, fm=lane&15, kg=lane>>4;
  f32x4 acc[4][4] = {};
  for (int k0=0; k0<ICt; k0+=32){
    for (int tap=0; tap<9; tap++){
      const size_t toff = (size_t)((tap/3)*66 + (tap%3))*ICt + k0;
      const size_t woff = (size_t)tap*wtap + k0;
      __syncthreads();                 // previous iteration's reads done
      gld16(xg[0]+toff, lA0);
      gld16(xg[1]+toff, lA1);
      gld16(wg[0]+woff, lB0);
      gld16(wg[1]+woff, lB1);
      __syncthreads();                 // compiler drains vmcnt before barrier -> data landed
      bf16x8 af[4], bfr[4];
#pragma unroll
      for(int i=0;i<4;i++) af[i]  = *(const bf16x8*)&As[(wr+i*16+fm)*32 + kg*8];
#pragma unroll
      for(int j=0;j<4;j++) bfr[j] = *(const bf16x8*)&Bs[(wc+j*16+fm)*32 + kg*8];
#pragma unroll
      for(int i=0;i<4;i++)
#pragma unroll
        for(int j=0;j<4;j++)
          acc[i][j] = __builtin_amdgcn_mfma_f32_16x16x32_bf16(af[i], bfr[j], acc[i][j], 0,0,0);
    }
  }
#pragma unroll
  for(int j=0;j<4;j++){
    int col = n0 + wc + j*16 + fm;
    float s = bf2f(scb[col]), bb = bf2f(bib[col]);
#pragma unroll
    for(int i=0;i<4;i++){
      int row = m0 + wr + i*16 + (kg<<2);
#pragma unroll
      for(int rr=0;rr<4;rr++){
        size_t idx = (size_t)(row+rr)*512 + col;
        float v = acc[i][j][rr];
        if (phase == 0)      Ob[idx] = f2bf(v);
        else if (phase == 1) Ob[idx] = f2bf(fmaxf(s*(bf2f(Ob[idx]) + v) + bb, 0.f));
        else                 Ob[idx] = f2bf(fmaxf(s*v + bb, 0.f));
      }
    }
  }
}

// PAM row softmax, in-place over rows of 4096 bf16
__global__ __launch_bounds__(256) void k_softmax_pam(u16* __restrict__ attn){
  __shared__ float red[8];
  u16* row = attn + (size_t)blockIdx.x*4096;
  uint4* rv = (uint4*)row;
  const int t = threadIdx.x;
  uint4 c0 = rv[2*t], c1 = rv[2*t+1];
  u16* e0 = (u16*)&c0; u16* e1=(u16*)&c1;
  float v[16];
#pragma unroll
  for(int i=0;i<8;i++){ v[i]=bf2f(e0[i]); v[8+i]=bf2f(e1[i]); }
  float mx = v[0];
#pragma unroll
  for(int i=1;i<16;i++) mx = fmaxf(mx, v[i]);
  mx = wave_max(mx);
  if((t&63)==0) red[t>>6] = mx;
  __syncthreads();
  mx = fmaxf(fmaxf(red[0],red[1]),fmaxf(red[2],red[3]));
  float s = 0.f;
#pragma unroll
  for(int i=0;i<16;i++){ v[i]=__expf(v[i]-mx); s += v[i]; }
  s = wave_sum(s);
  if((t&63)==0) red[4+(t>>6)] = s;
  __syncthreads();
  s = red[4]+red[5]+red[6]+red[7];
  float inv = 1.f/s;
#pragma unroll
  for(int i=0;i<8;i++){ e0[i]=f2bf(v[i]*inv); e1[i]=f2bf(v[8+i]*inv); }
  rv[2*t]=c0; rv[2*t+1]=c1;
}

// PV split-K combine: io = f2bf(alpha * (P0+P1+P2+P3) + io)   (4 splits of 2048x512 f32)
__global__ __launch_bounds__(256) void k_pv_combine(const float* __restrict__ Pp, u16* __restrict__ io,
                                                    const u16* __restrict__ alpha){
  const int i = blockIdx.x*256 + threadIdx.x;     // float4 index, 262144 total
  const float4* p = (const float4*)Pp;
  float4 a0 = p[i], a1 = p[i+262144], a2 = p[i+524288], a3 = p[i+786432];
  const float al = bf2f(alpha[0]);
  ushort4 d = ((const ushort4*)io)[i];
  ushort4 o;
  o.x = f2bf(al*(a0.x+a1.x+a2.x+a3.x) + bf2f(d.x));
  o.y = f2bf(al*(a0.y+a1.y+a2.y+a3.y) + bf2f(d.y));
  o.z = f2bf(al*(a0.z+a1.z+a2.z+a3.z) + bf2f(d.z));
  o.w = f2bf(al*(a0.w+a1.w+a2.w+a3.w) + bf2f(d.w));
  ((ushort4*)io)[i] = o;
}

// CAM softmax over split-K partial sums: out[c][d] = softmax_d(-(sum of 8 partials))
__global__ __launch_bounds__(256) void k_softmax_cam8(const float* __restrict__ P8, u16* __restrict__ outp){
  __shared__ float red[8];
  const int t = threadIdx.x;
  const float* r0 = P8 + (size_t)blockIdx.x*512;  // split stride 262144 floats (512x512)
  float a = 0.f, b2 = 0.f;
#pragma unroll
  for(int s2=0;s2<8;s2++){ a += r0[(size_t)s2*262144 + t]; b2 += r0[(size_t)s2*262144 + 256 + t]; }
  a = -a; b2 = -b2;
  float mx = wave_max(fmaxf(a,b2));
  if((t&63)==0) red[t>>6]=mx;
  __syncthreads();
  mx = fmaxf(fmaxf(red[0],red[1]),fmaxf(red[2],red[3]));
  float ea = __expf(a-mx), eb = __expf(b2-mx);
  float s = wave_sum(ea+eb);
  if((t&63)==0) red[4+(t>>6)]=s;
  __syncthreads();
  s = red[4]+red[5]+red[6]+red[7];
  float inv = 1.f/s;
  u16* orow = outp + (size_t)blockIdx.x*512;
  orow[t] = f2bf(ea*inv); orow[t+256] = f2bf(eb*inv);
}

// bilinear 2x upsample (half-pixel, clamp), NHWC[16384][81] -> NCHW out (f32 or bf16 per flag)
__global__ __launch_bounds__(128) void k_upsample(const u16* __restrict__ hp, const u16* __restrict__ hc,
                                                  const u16* __restrict__ hf, void* __restrict__ outp,
                                                  const int* __restrict__ flag){
  int bx = blockIdx.x;
  const int y = bx & 127; bx >>= 7;
  const int ch = bx % 81; bx /= 81;
  const int b = bx & 3; const int head = bx >> 2;
  const u16* src = (head==0) ? hp : (head==1 ? hc : hf);
  const int xo = threadIdx.x;
  float fy = y*0.5f - 0.25f, fx = xo*0.5f - 0.25f;
  float fy0 = floorf(fy), fx0 = floorf(fx);
  float wy = fy - fy0, wx = fx - fx0;
  int y0 = max((int)fy0, 0), y1 = min((int)fy0 + 1, 63);
  int x0 = max((int)fx0, 0), x1 = min((int)fx0 + 1, 63);
  const size_t bb = (size_t)b*4096;
  float v00 = bf2f(src[(bb + y0*64 + x0)*81 + ch]);
  float v01 = bf2f(src[(bb + y0*64 + x1)*81 + ch]);
  float v10 = bf2f(src[(bb + y1*64 + x0)*81 + ch]);
  float v11 = bf2f(src[(bb + y1*64 + x1)*81 + ch]);
  float v = (1.f-wy)*((1.f-wx)*v00 + wx*v01) + wy*((1.f-wx)*v10 + wx*v11);
  size_t oidx = ((size_t)(head*324 + b*81 + ch))*16384 + (size_t)y*128 + xo;
  if (*flag) ((float*)outp)[oidx] = v;
  else       ((u16*)outp)[oidx]  = f2bf(v);
}

extern "C" void kernel_launch(void* const* d_in, const int* in_sizes, int n_in,
                              void* d_out, int out_size, void* d_ws, size_t ws_size,
                              hipStream_t stream)
{
  (void)in_sizes; (void)n_in;
  const void* x   = d_in[0];
  const void* wp1 = d_in[1];
  const void* wc1 = d_in[4];
  const void* wp2 = d_in[15];
  const void* wc2 = d_in[18];
  char* ws = (char*)d_ws;
  const size_t MB = 1048576;
  auto P = [&](size_t off){ return (u16*)(ws + off); };

  // ws probe: plan needs 58 MiB of workspace.
  // d_out is used as scratch; out_size is an ELEMENT count. Worst-case capacity = out_size*2
  // bytes (bf16 output); we need 18 MiB of scratch.
  if (ws_size < 58*MB || (long)out_size*2 < (long)18*MB){
    k_sentinel<<<1,1,0,stream>>>((u16*)d_out, 16.0f * (float)(ws_size / MB));
    return;
  }

  // ws regions (MiB offsets; params region [56,58) never aliased):
  //  conv1: FP1 [0,16) FC1 [16,32) WTCP [32,41) WTCC [41,50)      (padded x chunk in d_out, 17.9MB)
  //  PAM:   FB [32,36) (fb|fc merged, ld=128) FDTb [36,40) PV-partials [40,56)  (ATTN chunk in d_out, 16MB)
  //  CAM:   FATb [32,36) FEATC [40,56)      (Gram split-8 partials 8MB + softmax out in d_out)
  //  conv2: WT2P [16,20.5) WT2C [20.5,25)                          (padded strip in d_out, 17.9MB)
  //  heads: FUS [16,32) HP [32,35) HC [35,38) HF [38,40.6) -- HF clobbers FEATC head AFTER HC gemm
  const size_t FP1=0, FC1=16*MB, WTCP=32*MB, WTCC=41*MB,
               FB=32*MB, FDTb=36*MB, PP=40*MB,
               FATb=32*MB, FEATC=40*MB,
               WT2P=16*MB, WT2C=WT2P+4718592,
               FUS=16*MB, HP=32*MB, HC=35*MB, HF=38*MB;
  u16* prm = P(56*MB);
  int* FLAG = (int*)(ws + 57*MB + 524288);
  u16* SCR = (u16*)d_out;   // d_out used as scratch; fully overwritten by k_upsample at the end
  const int SP1=0, BP1=512, SC1=1024, BC1=1536, SP2=2048, BP2=2560, SC2=3072, BC2=3584,
            PBB=4096, PBC=4160, PBD=4224, BP3=4736, BC3=4817, BLOG=4898, ALPHA=4979, BETA=4980,
            PWB=4992, PWC=37760, PWD=70528, W3P=332672, W3C=374144, W3L=415616;

  // ---- dtype probe + param normalization to bf16 ----
  k_probe<<<1, 256, 0, stream>>>((const unsigned*)x, FLAG);
  auto cv = [&](int di, int po, int n){
    k_cvt<<<(n+255)/256, 256, 0, stream>>>(d_in[di], prm+po, n, FLAG);
  };
  cv(2,SP1,512);  cv(3,BP1,512);  cv(5,SC1,512);  cv(6,BC1,512);
  cv(16,SP2,512); cv(17,BP2,512); cv(19,SC2,512); cv(20,BC2,512);
  cv(8,PBB,64);   cv(10,PBC,64);  cv(12,PBD,512);
  cv(24,BP3,81);  cv(26,BC3,81);  cv(22,BLOG,81);
  cv(13,ALPHA,1); cv(14,BETA,1);
  cv(7,PWB,32768); cv(9,PWC,32768); cv(11,PWD,262144);
  cv(23,W3P,41472); cv(25,W3C,41472); cv(21,W3L,41472);

  // ---- conv1 (2048->512), 2 ic-chunks of 1024, 2 batches per dispatch, P+C branch folded ----
  // 2-batch padded chunk = 17.9 MB in d_out. gridDim.y=64 (8 m-tiles/XCD band).
  // Phases 0 -> 1: single intermediate bf16 rounding (proven absmax 0.0977).
  const int BPD = 2;
  const int nbp = 4/BPD;
  k_zero<<<BPD*2178, 256, 0, stream>>>((uint4*)SCR, (long)BPD*557568);  // BPD*66*66*1024 bf16
  for (int ch=0; ch<2; ch++){
    k_wtrans2<<<dim3(16,128), 256, 0, stream>>>(wp1, P(WTCP), 2048, 1024, ch*1024, FLAG);
    k_wtrans2<<<dim3(16,128), 256, 0, stream>>>(wc1, P(WTCC), 2048, 1024, ch*1024, FLAG);
    for (int bp=0; bp<nbp; bp++){
      k_pad1<<<dim3(64,16,BPD), 256, 0, stream>>>(x, SCR, 1024, ch*1024, bp*BPD, FLAG);
      const size_t ob = (size_t)bp*BPD*4096*512;
      conv3_gemm<<<dim3(8,32*BPD), 256, 0, stream>>>(SCR, P(WTCP), 1024, P(FP1)+ob, prm+SP1, prm+BP1, ch,
                                                     4718592L, 8388608L);
    }
  }

  // ---- PAM (writes feat_p in-place over FP1) ----
  // FB/FCc merged: PWB|PWC adjacent (N=128), PBB|PBC adjacent; out [16384][128] (fb=cols 0-63, fc=64-127)
  gemm_nt<<<dim3(1,128), 256, 0, stream>>>(P(FP1), prm+PWB, 128, 512, 512, 512, P(FB), 128, 1, prm+PBB, nullptr, 0, 0);
  for (int b=0;b<4;b++){
    const size_t fo = (size_t)b*4096*128, so = (size_t)b*4096*512;
    // FD^T directly: C[c][m] = sum_ic wd[c][ic]*feat_p[m][ic] + bd[c]  (mode 5 = row bias)
    gemm_nt<<<dim3(32,4), 256, 0, stream>>>(prm+PWD, P(FP1)+so, 4096, 512, 512, 512, P(FDTb), 4096, 5, prm+PBD, nullptr, 0, 0);
    for (int ck=0;ck<2;ck++){
      // attn chunk [2048][4096] in d_out (A = fb rows, B = fc rows; both ld=128)
      gemm_nt<<<dim3(32,16), 256, 0, stream>>>(P(FB)+fo+(size_t)ck*262144, P(FB)+64+fo, 4096, 64, 128, 128, SCR, 4096, 0, nullptr, nullptr, 0, 0);
      k_softmax_pam<<<2048, 256, 0, stream>>>(SCR);
      // PV split-K=4 into f32 partials, then combine with alpha + residual (in-place FP1)
      gemm_nt<<<dim3(4,16,4), 256, 0, stream>>>(SCR, P(FDTb), 512, 4096, 4096, 4096, (void*)P(PP), 512, 4, nullptr, nullptr, 1024, 4194304);
      k_pv_combine<<<1024, 256, 0, stream>>>((const float*)P(PP), P(FP1)+so+(size_t)ck*1048576, prm+ALPHA);
    }
  }

  // ---- CAM (per-batch; FEATC separate buffer; Gram matrix split-K=8, partials in d_out) ----
  u16* ATTCS = SCR + 4194304;   // after the 8MB partial region
  for (int b=0;b<4;b++){
    const size_t so = (size_t)b*4096*512;
    k_transpose<<<dim3(8,64), 256, 0, stream>>>(P(FC1)+so, P(FATb), 4096, 512);
    gemm_nt<<<dim3(4,4,8), 256, 0, stream>>>(P(FATb), P(FATb), 512, 4096, 4096, 4096, (void*)SCR, 512, 4, nullptr, nullptr, 512, 1048576);
    k_softmax_cam8<<<512, 256, 0, stream>>>((const float*)SCR, ATTCS);
    gemm_nt<<<dim3(4,32), 256, 0, stream>>>(P(FC1)+so, ATTCS, 512, 512, 512, 512, P(FEATC)+so, 512, 3, prm+BETA, P(FC1)+so, 0, 0);
  }

  // ---- conv2 pair (all-batch padded strip in d_out, in-place over FP1 / FEATC) ----
  k_wtrans2<<<dim3(8,128), 256, 0, stream>>>(wp2, P(WT2P), 512, 512, 0, FLAG);
  k_wtrans2<<<dim3(8,128), 256, 0, stream>>>(wc2, P(WT2C), 512, 512, 0, FLAG);
  k_zero<<<4356, 256, 0, stream>>>((uint4*)SCR, 1115136);  // 4*66*66*512 bf16
  k_pad_strip<<<4096, 256, 0, stream>>>(P(FP1), SCR, 512, 16384);
  conv3_gemm<<<dim3(4,128), 256, 0, stream>>>(SCR, P(WT2P), 512, P(FP1), prm+SP2, prm+BP2, 2, 0L, 0L);
  k_pad_strip<<<4096, 256, 0, stream>>>(P(FEATC), SCR, 512, 16384);
  conv3_gemm<<<dim3(4,128), 256, 0, stream>>>(SCR, P(WT2C), 512, P(FEATC), prm+SC2, prm+BC2, 2, 0L, 0L);

  // ---- heads + upsample ----
  k_add_bf16<<<4096, 256, 0, stream>>>(P(FP1), P(FEATC), P(FUS), (long)16384*512);
  gemm_nt<<<dim3(1,128), 256, 0, stream>>>(P(FP1), prm+W3P, 81, 512, 512, 512, P(HP), 81, 1, prm+BP3, nullptr, 0, 0);
  gemm_nt<<<dim3(1,128), 256, 0, stream>>>(P(FEATC), prm+W3C, 81, 512, 512, 512, P(HC), 81, 1, prm+BC3, nullptr, 0, 0);
  // HF region overlaps FEATC's first MiBs -- must run after HC gemm (stream-ordered).
  gemm_nt<<<dim3(1,128), 256, 0, stream>>>(P(FUS), prm+W3L, 81, 512, 512, 512, P(HF), 81, 1, prm+BLOG, nullptr, 0, 0);
  k_upsample<<<124416, 128, 0, stream>>>(P(HP), P(HC), P(HF), d_out, FLAG);
}